// Round 2
// 514.004 us; speedup vs baseline: 1.3139x; 1.3139x over previous
//
#include <hip/hip_runtime.h>

typedef unsigned short u16;
typedef unsigned int u32;
typedef __bf16 bf16x8 __attribute__((ext_vector_type(8)));
typedef float floatx4 __attribute__((ext_vector_type(4)));

#define EPSF 1e-8f

__device__ __forceinline__ float bf2f(u16 u) { return __uint_as_float(((u32)u) << 16); }
__device__ __forceinline__ u16 f2bf(float f) {
  u32 u = __float_as_uint(f);
  u += 0x7fffu + ((u >> 16) & 1u);
  return (u16)(u >> 16);
}
__device__ __forceinline__ void unpack2(u32 u, float& a, float& b) {
  a = __uint_as_float(u << 16);
  b = __uint_as_float(u & 0xffff0000u);
}
__device__ __forceinline__ float wave_sum(float s) {
#pragma unroll
  for (int m = 32; m; m >>= 1) s += __shfl_xor(s, m, 64);
  return s;
}
// packed RNE f32->bf16 (v_cvt_pk_bf16_f32): dst.lo = bf16(lo), dst.hi = bf16(hi)
__device__ __forceinline__ u32 cvtpk(float lo, float hi) {
  u32 r;
  asm("v_cvt_pk_bf16_f32 %0, %1, %2" : "=v"(r) : "v"(lo), "v"(hi));
  return r;
}

typedef __attribute__((address_space(1))) void gv_t;
typedef __attribute__((address_space(3))) void lv_t;
__device__ __forceinline__ void gload_lds16(const u16* g, u16* l) {
  __builtin_amdgcn_global_load_lds((const gv_t*)g, (lv_t*)l, 16, 0, 0);
}

// Device-side dtype sniff: curvature == -1.0 always.
// f32 -1.0 = 0xBF800000, little-endian -> first u16 is 0x0000; bf16 -1.0 -> 0xBF80.
__device__ __forceinline__ bool sniff_f32(const void* curv) {
  return ((const u16*)curv)[0] == 0;
}
__device__ __forceinline__ uint4 load8bf(const void* base, size_t off, bool isf32) {
  if (!isf32) return *(const uint4*)((const u16*)base + off);
  const float* p = (const float*)base + off;
  float4 a = *(const float4*)p;
  float4 b = *(const float4*)(p + 4);
  uint4 r;
  r.x = (u32)f2bf(a.x) | ((u32)f2bf(a.y) << 16);
  r.y = (u32)f2bf(a.z) | ((u32)f2bf(a.w) << 16);
  r.z = (u32)f2bf(b.x) | ((u32)f2bf(b.y) << 16);
  r.w = (u32)f2bf(b.z) | ((u32)f2bf(b.w) << 16);
  return r;
}
__device__ __forceinline__ void load8f(const void* base, size_t off, bool isf32, float* o) {
  if (isf32) {
    const float* p = (const float*)base + off;
    float4 a = *(const float4*)p;
    float4 b = *(const float4*)(p + 4);
    o[0] = a.x; o[1] = a.y; o[2] = a.z; o[3] = a.w;
    o[4] = b.x; o[5] = b.y; o[6] = b.z; o[7] = b.w;
  } else {
    const u16* p = (const u16*)base + off;
    uint4 r = *(const uint4*)p;
    unpack2(r.x, o[0], o[1]);
    unpack2(r.y, o[2], o[3]);
    unpack2(r.z, o[4], o[5]);
    unpack2(r.w, o[6], o[7]);
  }
}

// ---------- convert kernel: f32 -> bf16 for node_features, to_w, from_w ----------
// No-op when inputs are already bf16 (device-side sniff). Memory-bound.
__global__ __launch_bounds__(256) void cvt_kernel(
    const float* __restrict__ A, const float* __restrict__ TW, const float* __restrict__ FW,
    u16* __restrict__ oA, u16* __restrict__ oTW, u16* __restrict__ oFW,
    const void* __restrict__ curv)
{
  if (!sniff_f32(curv)) return;
  const long CA = 37748736L / 8;  // node_features chunks of 8
  const long CW = 262144L / 8;    // one 512x512 weight matrix
  const long total = CA + 2 * CW;
  for (long i = (long)blockIdx.x * blockDim.x + threadIdx.x; i < total;
       i += (long)gridDim.x * blockDim.x) {
    const float* s; u16* d; long j;
    if (i < CA)           { s = A;  d = oA;  j = i; }
    else if (i < CA + CW) { s = TW; d = oTW; j = i - CA; }
    else                  { s = FW; d = oFW; j = i - CA - CW; }
    float4 a = *(const float4*)(s + j * 8);
    float4 b = *(const float4*)(s + j * 8 + 4);
    uint4 o;
    o.x = cvtpk(a.x, a.y);
    o.y = cvtpk(a.z, a.w);
    o.z = cvtpk(b.x, b.y);
    o.w = cvtpk(b.z, b.w);
    *(uint4*)(d + j * 8) = o;
  }
}

// ---------- unified bf16 GEMM: C[M,N] = A[M,K] @ B[N,K]^T + bias ----------
// 128x128x32 tiles, global_load_lds width-16 staging (m97 structure).
// A/B source pointers selected on device by dtype sniff (orig = bf16 inputs,
// conv = bf16 copies made by cvt_kernel when inputs are f32).
// FINAL=1: store output in input dtype (f32 or bf16); FINAL=0: always bf16.
template <int FINAL>
__global__ __launch_bounds__(256) void gemm_fast(
    const void* __restrict__ origA, const u16* __restrict__ convA,
    const void* __restrict__ origB, const u16* __restrict__ convB,
    const void* __restrict__ bias, void* __restrict__ out,
    const void* __restrict__ curv, int M, int N, int K)
{
  __shared__ __align__(16) u16 As[128 * 32];
  __shared__ __align__(16) u16 Bs[128 * 32];

  const bool f32 = sniff_f32(curv);
  const u16* A = f32 ? convA : (const u16*)origA;
  const u16* B = f32 ? convB : (const u16*)origB;

  const int t = threadIdx.x;
  const int lane = t & 63;
  const int w = t >> 6;
  const int waveM = w >> 1, waveN = w & 1;
  const int m0 = blockIdx.y * 128;
  const int n0 = blockIdx.x * 128;

  floatx4 acc[4][4];
#pragma unroll
  for (int i = 0; i < 4; i++)
#pragma unroll
    for (int j = 0; j < 4; j++) {
      acc[i][j][0] = 0.f; acc[i][j][1] = 0.f;
      acc[i][j][2] = 0.f; acc[i][j][3] = 0.f;
    }

  // Staging: thread t covers LDS byte offset t*16 of each 4KB half-tile
  // (row = t>>2, 16B at col (t&3)*8). global_load_lds LDS dest is
  // wave-uniform base + lane*16 -> base = half_base + w*1024B.
  const u16* ga0 = A + (size_t)(m0 + (t >> 2)) * K + (t & 3) * 8;
  const u16* ga1 = ga0 + (size_t)64 * K;
  const u16* gb0 = B + (size_t)(n0 + (t >> 2)) * K + (t & 3) * 8;
  const u16* gb1 = gb0 + (size_t)64 * K;
  u16* lA0 = As + w * 512;          // bytes: w*1024
  u16* lA1 = As + 2048 + w * 512;   // second 64 rows at byte 4096
  u16* lB0 = Bs + w * 512;
  u16* lB1 = Bs + 2048 + w * 512;

  const int am = waveM * 64 + (lane & 15);
  const int bn = waveN * 64 + (lane & 15);
  const int kq = (lane >> 4) * 8;

  for (int k0 = 0; k0 < K; k0 += 32) {
    gload_lds16(ga0 + k0, lA0);
    gload_lds16(ga1 + k0, lA1);
    gload_lds16(gb0 + k0, lB0);
    gload_lds16(gb1 + k0, lB1);
    __syncthreads();  // drains vmcnt(0): LDS tile ready

    bf16x8 af[4], bfr[4];
#pragma unroll
    for (int mt = 0; mt < 4; mt++)
      af[mt] = *(const bf16x8*)(As + (am + mt * 16) * 32 + kq);
#pragma unroll
    for (int nt = 0; nt < 4; nt++)
      bfr[nt] = *(const bf16x8*)(Bs + (bn + nt * 16) * 32 + kq);
#pragma unroll
    for (int mt = 0; mt < 4; mt++)
#pragma unroll
      for (int nt = 0; nt < 4; nt++)
        acc[mt][nt] = __builtin_amdgcn_mfma_f32_16x16x32_bf16(af[mt], bfr[nt], acc[mt][nt], 0, 0, 0);
    __syncthreads();  // all reads done before next stage overwrites
  }

  const int quad = lane >> 4;
  const int cl = lane & 15;
#pragma unroll
  for (int mt = 0; mt < 4; mt++)
#pragma unroll
    for (int nt = 0; nt < 4; nt++) {
      const int col = n0 + waveN * 64 + nt * 16 + cl;
      const float bs = f32 ? ((const float*)bias)[col] : bf2f(((const u16*)bias)[col]);
#pragma unroll
      for (int r = 0; r < 4; r++) {
        const int row = m0 + waveM * 64 + mt * 16 + quad * 4 + r;
        const float v = acc[mt][nt][r] + bs;
        if (FINAL && f32) ((float*)out)[(size_t)row * N + col] = v;
        else              ((u16*)out)[(size_t)row * N + col] = f2bf(v);
      }
    }
}

// ---------- Mobius: in-place on the bf16 intermediate. One block per batch elem. ----------
// X = f32(sniff) ? Xf : Xb  (fast path passes the same pointer twice).
__global__ __launch_bounds__(256) void mobius2(
    u16* Xf, u16* Xb, const void* __restrict__ MW, const void* __restrict__ curv)
{
  __shared__ float h[9][512];
  __shared__ float hh[9];

  const bool f32 = sniff_f32(curv);
  u16* X = f32 ? Xf : Xb;

  const int b = blockIdx.x;
  const int t = threadIdx.x;
  const int lane = t & 63;
  const int w = t >> 6;
  const float c = f32 ? fabsf(((const float*)curv)[0]) : fabsf(bf2f(((const u16*)curv)[0]));

  for (int r = w; r < 9; r += 4) {
    uint4 raw = *(const uint4*)(X + ((size_t)b * 9 + r) * 512 + lane * 8);
    float x[8];
    unpack2(raw.x, x[0], x[1]);
    unpack2(raw.y, x[2], x[3]);
    unpack2(raw.z, x[4], x[5]);
    unpack2(raw.w, x[6], x[7]);
    float s = 0.f;
#pragma unroll
    for (int p = 0; p < 8; p++) s += x[p] * x[p];
    s = wave_sum(s);
    const float norm = sqrtf(s);
    const float scale = tanhf(norm) / (norm + EPSF);
#pragma unroll
    for (int p = 0; p < 8; p++) h[r][lane * 8 + p] = x[p] * scale;
    if (lane == 0) hh[r] = scale * scale * s;
  }
  __syncthreads();

  const int baseNode[4] = {8, 0, 3, 6};
  const int cntNode[4] = {1, 3, 3, 2};
  const int nbrCnt[9] = {3, 3, 2, 3, 3, 2, 3, 3, 8};
  const int nbrTab[9][8] = {
      {4, 7, 8, 0, 0, 0, 0, 0}, {0, 6, 8, 0, 0, 0, 0, 0}, {5, 8, 0, 0, 0, 0, 0, 0},
      {1, 4, 8, 0, 0, 0, 0, 0}, {6, 3, 8, 0, 0, 0, 0, 0}, {2, 8, 0, 0, 0, 0, 0, 0},
      {7, 1, 8, 0, 0, 0, 0, 0}, {3, 0, 8, 0, 0, 0, 0, 0}, {0, 1, 2, 3, 4, 5, 6, 7}};

  for (int s = 0; s < cntNode[w]; s++) {
    const int i = baseNode[w] + s;
    float r8[8];
#pragma unroll
    for (int p = 0; p < 8; p++) r8[p] = h[i][lane * 8 + p];
    float rr = 0.f;
#pragma unroll
    for (int p = 0; p < 8; p++) rr += r8[p] * r8[p];
    rr = wave_sum(rr);

    for (int e = 0; e < nbrCnt[i]; e++) {
      const int j = nbrTab[i][e];
      float y[8];
      load8f(MW, ((size_t)i * 9 + j) * 512 + lane * 8, f32, y);
      float x8[8];
#pragma unroll
      for (int p = 0; p < 8; p++) x8[p] = h[j][lane * 8 + p];
      const float xx = hh[j];
      float xy = 0.f, yy = 0.f;
#pragma unroll
      for (int p = 0; p < 8; p++) { xy += x8[p] * y[p]; yy += y[p] * y[p]; }
#pragma unroll
      for (int m = 32; m; m >>= 1) {
        xy += __shfl_xor(xy, m, 64);
        yy += __shfl_xor(yy, m, 64);
      }
      const float a1 = 1.f + 2.f * c * xy + c * yy;
      const float b1 = 1.f - c * xx;
      const float inv1 = 1.f / (1.f + 2.f * c * xy + c * c * xx * yy + EPSF);
      float t8[8];
#pragma unroll
      for (int p = 0; p < 8; p++) t8[p] = (a1 * x8[p] + b1 * y[p]) * inv1;
      float tt = 0.f, rt = 0.f;
#pragma unroll
      for (int p = 0; p < 8; p++) { tt += t8[p] * t8[p]; rt += r8[p] * t8[p]; }
#pragma unroll
      for (int m = 32; m; m >>= 1) {
        tt += __shfl_xor(tt, m, 64);
        rt += __shfl_xor(rt, m, 64);
      }
      const float a2 = 1.f + 2.f * c * rt + c * tt;
      const float b2 = 1.f - c * rr;
      const float inv2 = 1.f / (1.f + 2.f * c * rt + c * c * rr * tt + EPSF);
      float nrr = 0.f;
#pragma unroll
      for (int p = 0; p < 8; p++) {
        r8[p] = (a2 * r8[p] + b2 * t8[p]) * inv2;
        nrr += r8[p] * r8[p];
      }
      rr = wave_sum(nrr);
    }

    uint4 o;
    o.x = (u32)f2bf(r8[0]) | ((u32)f2bf(r8[1]) << 16);
    o.y = (u32)f2bf(r8[2]) | ((u32)f2bf(r8[3]) << 16);
    o.z = (u32)f2bf(r8[4]) | ((u32)f2bf(r8[5]) << 16);
    o.w = (u32)f2bf(r8[6]) | ((u32)f2bf(r8[7]) << 16);
    *(uint4*)(X + ((size_t)b * 9 + i) * 512 + lane * 8) = o;
  }
}

// ================= FALLBACK PATH (previous session's verified kernels) =================
__global__ __launch_bounds__(256) void gemm1_bt_bias(
    const void* __restrict__ A, const void* __restrict__ Bw,
    const void* __restrict__ bias, void* out, void* ws,
    const void* __restrict__ curv, int M, int N, int K)
{
  __shared__ __align__(16) u16 As[128 * 32];
  __shared__ __align__(16) u16 Bs[128 * 32];

  const bool f32 = sniff_f32(curv);
  u16* C = f32 ? (u16*)ws : (u16*)out;

  const int t = threadIdx.x;
  const int lane = t & 63;
  const int w = t >> 6;
  const int waveM = w >> 1, waveN = w & 1;
  const int m0 = blockIdx.y * 128;
  const int n0 = blockIdx.x * 128;

  floatx4 acc[4][4];
#pragma unroll
  for (int i = 0; i < 4; i++)
#pragma unroll
    for (int j = 0; j < 4; j++) {
      acc[i][j][0] = 0.f; acc[i][j][1] = 0.f;
      acc[i][j][2] = 0.f; acc[i][j][3] = 0.f;
    }

  const int r0 = t >> 2;
  const int c0 = (t & 3) * 8;
  const size_t oa0 = (size_t)(m0 + r0) * K + c0;
  const size_t oa1 = (size_t)(m0 + 64 + r0) * K + c0;
  const size_t ob0 = (size_t)(n0 + r0) * K + c0;
  const size_t ob1 = (size_t)(n0 + 64 + r0) * K + c0;

  for (int k0 = 0; k0 < K; k0 += 32) {
    uint4 a0 = load8bf(A, oa0 + k0, f32);
    uint4 a1 = load8bf(A, oa1 + k0, f32);
    uint4 b0 = load8bf(Bw, ob0 + k0, f32);
    uint4 b1 = load8bf(Bw, ob1 + k0, f32);
    __syncthreads();
    *(uint4*)(As + t * 8) = a0;
    *(uint4*)(As + 2048 + t * 8) = a1;
    *(uint4*)(Bs + t * 8) = b0;
    *(uint4*)(Bs + 2048 + t * 8) = b1;
    __syncthreads();

    bf16x8 af[4], bfr[4];
    const int am = waveM * 64 + (lane & 15);
    const int bn = waveN * 64 + (lane & 15);
    const int kq = (lane >> 4) * 8;
#pragma unroll
    for (int mt = 0; mt < 4; mt++)
      af[mt] = *(const bf16x8*)(As + (am + mt * 16) * 32 + kq);
#pragma unroll
    for (int nt = 0; nt < 4; nt++)
      bfr[nt] = *(const bf16x8*)(Bs + (bn + nt * 16) * 32 + kq);
#pragma unroll
    for (int mt = 0; mt < 4; mt++)
#pragma unroll
      for (int nt = 0; nt < 4; nt++)
        acc[mt][nt] = __builtin_amdgcn_mfma_f32_16x16x32_bf16(af[mt], bfr[nt], acc[mt][nt], 0, 0, 0);
  }

  const int quad = lane >> 4;
  const int cl = lane & 15;
#pragma unroll
  for (int mt = 0; mt < 4; mt++)
#pragma unroll
    for (int nt = 0; nt < 4; nt++) {
      const int col = n0 + waveN * 64 + nt * 16 + cl;
      const float bs = f32 ? ((const float*)bias)[col] : bf2f(((const u16*)bias)[col]);
#pragma unroll
      for (int r = 0; r < 4; r++) {
        const int row = m0 + waveM * 64 + mt * 16 + quad * 4 + r;
        C[(size_t)row * N + col] = f2bf(acc[mt][nt][r] + bs);
      }
    }
}

__global__ __launch_bounds__(256) void gemm2_fullN(
    const void* __restrict__ Bw, const void* __restrict__ bias,
    void* out, void* ws, const void* __restrict__ curv,
    int M, int N, int K)
{
  __shared__ __align__(16) u16 As[32 * 32];
  __shared__ __align__(16) u16 Bs[512 * 32];

  const bool f32 = sniff_f32(curv);
  const u16* A = f32 ? (const u16*)ws : (const u16*)out;

  const int t = threadIdx.x;
  const int lane = t & 63;
  const int w = t >> 6;
  const int m0 = blockIdx.x * 32;

  floatx4 acc[2][8];
#pragma unroll
  for (int i = 0; i < 2; i++)
#pragma unroll
    for (int j = 0; j < 8; j++) {
      acc[i][j][0] = 0.f; acc[i][j][1] = 0.f;
      acc[i][j][2] = 0.f; acc[i][j][3] = 0.f;
    }

  const int r0 = t >> 2;
  const int c0 = (t & 3) * 8;

  for (int k0 = 0; k0 < K; k0 += 32) {
    uint4 av = make_uint4(0, 0, 0, 0);
    if (t < 128)
      av = *(const uint4*)(A + (size_t)(m0 + r0) * K + k0 + c0);
    uint4 bv[8];
#pragma unroll
    for (int q = 0; q < 8; q++)
      bv[q] = load8bf(Bw, (size_t)(q * 64 + r0) * K + k0 + c0, f32);
    __syncthreads();
    if (t < 128) *(uint4*)(As + t * 8) = av;
#pragma unroll
    for (int q = 0; q < 8; q++)
      *(uint4*)(Bs + q * 2048 + t * 8) = bv[q];
    __syncthreads();

    bf16x8 af[2], bfr[8];
    const int ml = lane & 15;
    const int kq = (lane >> 4) * 8;
#pragma unroll
    for (int mt = 0; mt < 2; mt++)
      af[mt] = *(const bf16x8*)(As + (mt * 16 + ml) * 32 + kq);
#pragma unroll
    for (int nt = 0; nt < 8; nt++)
      bfr[nt] = *(const bf16x8*)(Bs + (w * 128 + nt * 16 + ml) * 32 + kq);
#pragma unroll
    for (int mt = 0; mt < 2; mt++)
#pragma unroll
      for (int nt = 0; nt < 8; nt++)
        acc[mt][nt] = __builtin_amdgcn_mfma_f32_16x16x32_bf16(af[mt], bfr[nt], acc[mt][nt], 0, 0, 0);
  }

  const int quad = lane >> 4;
  const int cl = lane & 15;
#pragma unroll
  for (int mt = 0; mt < 2; mt++)
#pragma unroll
    for (int nt = 0; nt < 8; nt++) {
      const int col = w * 128 + nt * 16 + cl;
      const float bs = f32 ? ((const float*)bias)[col] : bf2f(((const u16*)bias)[col]);
#pragma unroll
      for (int r = 0; r < 4; r++) {
        const int row = m0 + mt * 16 + quad * 4 + r;
        const float v = acc[mt][nt][r] + bs;
        if (f32) ((float*)out)[(size_t)row * N + col] = v;
        else     ((u16*)out)[(size_t)row * N + col] = f2bf(v);
      }
    }
}

// ======================= launch =======================
extern "C" void kernel_launch(void* const* d_in, const int* in_sizes, int n_in,
                              void* d_out, int out_size, void* d_ws, size_t ws_size,
                              hipStream_t stream) {
  const void* nf = d_in[0];
  const void* curv = d_in[1];
  const void* to_w = d_in[2];
  const void* to_b = d_in[3];
  const void* fr_w = d_in[4];
  const void* fr_b = d_in[5];
  const void* mw = d_in[6];

  const int M = 8192 * 9, N = 512, K = 512;
  const size_t XB = (size_t)M * N * 2;       // 75,497,472 B  bf16 intermediate / A-copy
  const size_t WWB = (size_t)512 * 512 * 2;  // one 512x512 bf16 weight matrix

  // dtype is host-invisible (in_sizes are element counts; f32 and bf16 have the
  // same counts) -> all dtype decisions are device-side sniffs on curvature.
  // Host only picks the scratch LAYOUT from ws_size. d_out (151 MB when f32) can
  // host the bf16 A-copy/tw-copy: they are dead before gemm2 writes the output,
  // and in the bf16 case cvt_kernel writes nothing. fw must outlive into gemm2,
  // so it always lives in ws.
  u16 *xb = nullptr, *a_bf = nullptr, *tw_bf = nullptr, *fw_bf = nullptr;
  bool fast = false;
  if (ws_size >= 2 * XB + 2 * WWB) {          // everything in ws
    xb    = (u16*)d_ws;
    a_bf  = (u16*)((char*)d_ws + XB);
    tw_bf = (u16*)((char*)d_ws + 2 * XB);
    fw_bf = (u16*)((char*)d_ws + 2 * XB + WWB);
    fast = true;
  } else if (ws_size >= XB + 2 * WWB) {       // weights in ws, A-copy in d_out
    xb    = (u16*)d_ws;
    tw_bf = (u16*)((char*)d_ws + XB);
    fw_bf = (u16*)((char*)d_ws + XB + WWB);
    a_bf  = (u16*)d_out;
    fast = true;
  } else if (ws_size >= XB + WWB) {           // fw in ws, A-copy + tw in d_out
    xb    = (u16*)d_ws;
    fw_bf = (u16*)((char*)d_ws + XB);
    a_bf  = (u16*)d_out;
    tw_bf = (u16*)((char*)d_out + XB);
    fast = true;
  }

  if (fast) {
    cvt_kernel<<<2048, 256, 0, stream>>>((const float*)nf, (const float*)to_w,
                                         (const float*)fr_w, a_bf, tw_bf, fw_bf, curv);
    gemm_fast<0><<<dim3(N / 128, M / 128), 256, 0, stream>>>(
        nf, a_bf, to_w, tw_bf, to_b, xb, curv, M, N, K);
    mobius2<<<8192, 256, 0, stream>>>(xb, xb, mw, curv);
    gemm_fast<1><<<dim3(N / 128, M / 128), 256, 0, stream>>>(
        xb, xb, fr_w, fw_bf, fr_b, d_out, curv, M, N, K);
  } else {
    // fallback: previous session's verified path (needs ws >= XB only for f32)
    gemm1_bt_bias<<<dim3(N / 128, M / 128), 256, 0, stream>>>(nf, to_w, to_b, d_out, d_ws, curv, M, N, K);
    mobius2<<<8192, 256, 0, stream>>>((u16*)d_ws, (u16*)d_out, mw, curv);
    gemm2_fullN<<<M / 32, 256, 0, stream>>>(fr_w, fr_b, d_out, d_ws, curv, M, N, K);
  }
}

// Round 3
// 473.957 us; speedup vs baseline: 1.4249x; 1.0845x over previous
//
#include <hip/hip_runtime.h>

typedef unsigned short u16;
typedef unsigned int u32;
typedef __bf16 bf16x8 __attribute__((ext_vector_type(8)));
typedef float floatx4 __attribute__((ext_vector_type(4)));

#define EPSF 1e-8f

// mw-edge squared norms, computed on-device each launch (batch-independent).
__device__ float g_nrm[81];

__device__ __forceinline__ float bf2f(u16 u) { return __uint_as_float(((u32)u) << 16); }
__device__ __forceinline__ u16 f2bf(float f) {
  u32 u = __float_as_uint(f);
  u += 0x7fffu + ((u >> 16) & 1u);
  return (u16)(u >> 16);
}
__device__ __forceinline__ void unpack2(u32 u, float& a, float& b) {
  a = __uint_as_float(u << 16);
  b = __uint_as_float(u & 0xffff0000u);
}
__device__ __forceinline__ float wave_sum(float s) {
#pragma unroll
  for (int m = 32; m; m >>= 1) s += __shfl_xor(s, m, 64);
  return s;
}
// packed RNE f32->bf16 (v_cvt_pk_bf16_f32)
__device__ __forceinline__ u32 cvtpk(float lo, float hi) {
  u32 r;
  asm("v_cvt_pk_bf16_f32 %0, %1, %2" : "=v"(r) : "v"(lo), "v"(hi));
  return r;
}

typedef __attribute__((address_space(1))) void gv_t;
typedef __attribute__((address_space(3))) void lv_t;
__device__ __forceinline__ void gload_lds16(const u16* g, u16* l) {
  __builtin_amdgcn_global_load_lds((const gv_t*)g, (lv_t*)l, 16, 0, 0);
}

// Device-side dtype sniff: curvature == -1.0 always.
// f32 -1.0 = 0xBF800000 -> first u16 is 0x0000; bf16 -1.0 -> 0xBF80.
__device__ __forceinline__ bool sniff_f32(const void* curv) {
  return ((const u16*)curv)[0] == 0;
}
__device__ __forceinline__ uint4 load8bf(const void* base, size_t off, bool isf32) {
  if (!isf32) return *(const uint4*)((const u16*)base + off);
  const float* p = (const float*)base + off;
  float4 a = *(const float4*)p;
  float4 b = *(const float4*)(p + 4);
  uint4 r;
  r.x = (u32)f2bf(a.x) | ((u32)f2bf(a.y) << 16);
  r.y = (u32)f2bf(a.z) | ((u32)f2bf(a.w) << 16);
  r.z = (u32)f2bf(b.x) | ((u32)f2bf(b.y) << 16);
  r.w = (u32)f2bf(b.z) | ((u32)f2bf(b.w) << 16);
  return r;
}
__device__ __forceinline__ void load8f(const void* base, size_t off, bool isf32, float* o) {
  if (isf32) {
    const float* p = (const float*)base + off;
    float4 a = *(const float4*)p;
    float4 b = *(const float4*)(p + 4);
    o[0] = a.x; o[1] = a.y; o[2] = a.z; o[3] = a.w;
    o[4] = b.x; o[5] = b.y; o[6] = b.z; o[7] = b.w;
  } else {
    const u16* p = (const u16*)base + off;
    uint4 r = *(const uint4*)p;
    unpack2(r.x, o[0], o[1]);
    unpack2(r.y, o[2], o[3]);
    unpack2(r.z, o[4], o[5]);
    unpack2(r.w, o[6], o[7]);
  }
}

// ---------- mw norms: g_nrm[i*9+j] = ||mw[i][j]||^2 (batch-independent) ----------
__global__ __launch_bounds__(64) void mwnorm(const void* __restrict__ MW,
                                             const void* __restrict__ curv) {
  const bool f32 = sniff_f32(curv);
  const int e = blockIdx.x;       // 0..80
  const int lane = threadIdx.x;   // 0..63
  float y[8];
  load8f(MW, (size_t)e * 512 + lane * 8, f32, y);
  float s = 0.f;
#pragma unroll
  for (int p = 0; p < 8; p++) s += y[p] * y[p];
  s = wave_sum(s);
  if (lane == 0) g_nrm[e] = s;
}

// ---------- convert kernel: f32 -> bf16 for node_features, to_w, from_w ----------
__global__ __launch_bounds__(256) void cvt_kernel(
    const float* __restrict__ A, const float* __restrict__ TW, const float* __restrict__ FW,
    u16* __restrict__ oA, u16* __restrict__ oTW, u16* __restrict__ oFW,
    const void* __restrict__ curv)
{
  if (!sniff_f32(curv)) return;
  const long CA = 37748736L / 8;
  const long CW = 262144L / 8;
  const long total = CA + 2 * CW;
  for (long i = (long)blockIdx.x * blockDim.x + threadIdx.x; i < total;
       i += (long)gridDim.x * blockDim.x) {
    const float* s; u16* d; long j;
    if (i < CA)           { s = A;  d = oA;  j = i; }
    else if (i < CA + CW) { s = TW; d = oTW; j = i - CA; }
    else                  { s = FW; d = oFW; j = i - CA - CW; }
    float4 a = *(const float4*)(s + j * 8);
    float4 b = *(const float4*)(s + j * 8 + 4);
    uint4 o;
    o.x = cvtpk(a.x, a.y);
    o.y = cvtpk(a.z, a.w);
    o.z = cvtpk(b.x, b.y);
    o.w = cvtpk(b.z, b.w);
    *(uint4*)(d + j * 8) = o;
  }
}

// ---------- unified bf16 GEMM: C[M,N] = A[M,K] @ B[N,K]^T + bias ----------
// 128x128x32 tiles, global_load_lds width-16 staging. XCD-swizzled block map.
template <int FINAL>
__global__ __launch_bounds__(256) void gemm_fast(
    const void* __restrict__ origA, const u16* __restrict__ convA,
    const void* __restrict__ origB, const u16* __restrict__ convB,
    const void* __restrict__ bias, void* __restrict__ out,
    const void* __restrict__ curv, int M, int N, int K)
{
  __shared__ __align__(16) u16 As[128 * 32];
  __shared__ __align__(16) u16 Bs[128 * 32];

  const bool f32 = sniff_f32(curv);
  const u16* A = f32 ? convA : (const u16*)origA;
  const u16* B = f32 ? convB : (const u16*)origB;

  const int t = threadIdx.x;
  const int lane = t & 63;
  const int w = t >> 6;
  const int waveM = w >> 1, waveN = w & 1;

  // XCD-aware bijective swizzle: contiguous logical-tile chunk per XCD.
  int lid = blockIdx.x + blockIdx.y * gridDim.x;
  const int nwg = gridDim.x * gridDim.y;
  if ((nwg & 7) == 0) lid = (lid & 7) * (nwg >> 3) + (lid >> 3);
  const int m0 = (lid / gridDim.x) * 128;
  const int n0 = (lid % gridDim.x) * 128;

  floatx4 acc[4][4];
#pragma unroll
  for (int i = 0; i < 4; i++)
#pragma unroll
    for (int j = 0; j < 4; j++) {
      acc[i][j][0] = 0.f; acc[i][j][1] = 0.f;
      acc[i][j][2] = 0.f; acc[i][j][3] = 0.f;
    }

  const u16* ga0 = A + (size_t)(m0 + (t >> 2)) * K + (t & 3) * 8;
  const u16* ga1 = ga0 + (size_t)64 * K;
  const u16* gb0 = B + (size_t)(n0 + (t >> 2)) * K + (t & 3) * 8;
  const u16* gb1 = gb0 + (size_t)64 * K;
  u16* lA0 = As + w * 512;
  u16* lA1 = As + 2048 + w * 512;
  u16* lB0 = Bs + w * 512;
  u16* lB1 = Bs + 2048 + w * 512;

  const int am = waveM * 64 + (lane & 15);
  const int bn = waveN * 64 + (lane & 15);
  const int kq = (lane >> 4) * 8;

  for (int k0 = 0; k0 < K; k0 += 32) {
    gload_lds16(ga0 + k0, lA0);
    gload_lds16(ga1 + k0, lA1);
    gload_lds16(gb0 + k0, lB0);
    gload_lds16(gb1 + k0, lB1);
    __syncthreads();

    bf16x8 af[4], bfr[4];
#pragma unroll
    for (int mt = 0; mt < 4; mt++)
      af[mt] = *(const bf16x8*)(As + (am + mt * 16) * 32 + kq);
#pragma unroll
    for (int nt = 0; nt < 4; nt++)
      bfr[nt] = *(const bf16x8*)(Bs + (bn + nt * 16) * 32 + kq);
#pragma unroll
    for (int mt = 0; mt < 4; mt++)
#pragma unroll
      for (int nt = 0; nt < 4; nt++)
        acc[mt][nt] = __builtin_amdgcn_mfma_f32_16x16x32_bf16(af[mt], bfr[nt], acc[mt][nt], 0, 0, 0);
    __syncthreads();
  }

  const int quad = lane >> 4;
  const int cl = lane & 15;
#pragma unroll
  for (int mt = 0; mt < 4; mt++)
#pragma unroll
    for (int nt = 0; nt < 4; nt++) {
      const int col = n0 + waveN * 64 + nt * 16 + cl;
      const float bs = f32 ? ((const float*)bias)[col] : bf2f(((const u16*)bias)[col]);
#pragma unroll
      for (int r = 0; r < 4; r++) {
        const int row = m0 + waveM * 64 + mt * 16 + quad * 4 + r;
        const float v = acc[mt][nt][r] + bs;
        if (FINAL && f32) ((float*)out)[(size_t)row * N + col] = v;
        else              ((u16*)out)[(size_t)row * N + col] = f2bf(v);
      }
    }
}

// ---------- Mobius v3: algebraically reduced. In-place on bf16 intermediate. ----------
// Per edge (was 5 wave-reductions, ~150 VALU/lane): now 3 reductions (xy, rx, ry);
// yy from g_nrm; tt, rt, rr updated algebraically; t never materialized:
//   r' = ca*r + cx*x + cy*y.
__global__ __launch_bounds__(256) void mobius3(
    u16* Xf, u16* Xb, const void* __restrict__ MW, const void* __restrict__ curv)
{
  __shared__ float h[9][512];
  __shared__ float hh[9];

  const bool f32 = sniff_f32(curv);
  u16* X = f32 ? Xf : Xb;

  const int b = blockIdx.x;
  const int t = threadIdx.x;
  const int lane = t & 63;
  const int w = t >> 6;
  const float c = f32 ? fabsf(((const float*)curv)[0]) : fabsf(bf2f(((const u16*)curv)[0]));

  for (int r = w; r < 9; r += 4) {
    uint4 raw = *(const uint4*)(X + ((size_t)b * 9 + r) * 512 + lane * 8);
    float x[8];
    unpack2(raw.x, x[0], x[1]);
    unpack2(raw.y, x[2], x[3]);
    unpack2(raw.z, x[4], x[5]);
    unpack2(raw.w, x[6], x[7]);
    float s = 0.f;
#pragma unroll
    for (int p = 0; p < 8; p++) s += x[p] * x[p];
    s = wave_sum(s);
    const float norm = sqrtf(s);
    const float scale = tanhf(norm) / (norm + EPSF);
#pragma unroll
    for (int p = 0; p < 8; p++) h[r][lane * 8 + p] = x[p] * scale;
    if (lane == 0) hh[r] = scale * scale * s;
  }
  __syncthreads();

  const int baseNode[4] = {8, 0, 3, 6};
  const int cntNode[4] = {1, 3, 3, 2};
  const int nbrCnt[9] = {3, 3, 2, 3, 3, 2, 3, 3, 8};
  const int nbrTab[9][8] = {
      {4, 7, 8, 0, 0, 0, 0, 0}, {0, 6, 8, 0, 0, 0, 0, 0}, {5, 8, 0, 0, 0, 0, 0, 0},
      {1, 4, 8, 0, 0, 0, 0, 0}, {6, 3, 8, 0, 0, 0, 0, 0}, {2, 8, 0, 0, 0, 0, 0, 0},
      {7, 1, 8, 0, 0, 0, 0, 0}, {3, 0, 8, 0, 0, 0, 0, 0}, {0, 1, 2, 3, 4, 5, 6, 7}};

  for (int s = 0; s < cntNode[w]; s++) {
    const int i = baseNode[w] + s;
    float r8[8];
#pragma unroll
    for (int p = 0; p < 8; p++) r8[p] = h[i][lane * 8 + p];
    float rr = hh[i];  // ||r||^2 initial — no reduction needed

    for (int e = 0; e < nbrCnt[i]; e++) {
      const int j = nbrTab[i][e];
      float y[8];
      load8f(MW, ((size_t)i * 9 + j) * 512 + lane * 8, f32, y);
      float x8[8];
#pragma unroll
      for (int p = 0; p < 8; p++) x8[p] = h[j][lane * 8 + p];

      float xy = 0.f, rx = 0.f, ry = 0.f;
#pragma unroll
      for (int p = 0; p < 8; p++) {
        xy += x8[p] * y[p];
        rx += r8[p] * x8[p];
        ry += r8[p] * y[p];
      }
#pragma unroll
      for (int m = 32; m; m >>= 1) {
        xy += __shfl_xor(xy, m, 64);
        rx += __shfl_xor(rx, m, 64);
        ry += __shfl_xor(ry, m, 64);
      }

      const float xx = hh[j];
      const float yy = g_nrm[i * 9 + j];
      // t = mobius_add(x=h_j, y=mw_ij): t = inv1*(a1*x + b1*y)
      const float a1 = 1.f + 2.f * c * xy + c * yy;
      const float b1 = 1.f - c * xx;
      const float inv1 = 1.f / (1.f + 2.f * c * xy + c * c * xx * yy + EPSF);
      const float tt = inv1 * inv1 * (a1 * a1 * xx + 2.f * a1 * b1 * xy + b1 * b1 * yy);
      const float rt = inv1 * (a1 * rx + b1 * ry);
      // r' = mobius_add(x=r, y=t): r' = inv2*(a2*r + b2*t)
      const float a2 = 1.f + 2.f * c * rt + c * tt;
      const float b2 = 1.f - c * rr;
      const float inv2 = 1.f / (1.f + 2.f * c * rt + c * c * rr * tt + EPSF);
      const float ca = a2 * inv2;
      const float cb = b2 * inv2 * inv1;
      const float cx = cb * a1;
      const float cy = cb * b1;
#pragma unroll
      for (int p = 0; p < 8; p++)
        r8[p] = ca * r8[p] + cx * x8[p] + cy * y[p];
      rr = inv2 * inv2 * (a2 * a2 * rr + 2.f * a2 * b2 * rt + b2 * b2 * tt);
    }

    uint4 o;
    o.x = cvtpk(r8[0], r8[1]);
    o.y = cvtpk(r8[2], r8[3]);
    o.z = cvtpk(r8[4], r8[5]);
    o.w = cvtpk(r8[6], r8[7]);
    *(uint4*)(X + ((size_t)b * 9 + i) * 512 + lane * 8) = o;
  }
}

// ================= FALLBACK PATH (previous session's verified kernels) =================
__global__ __launch_bounds__(256) void gemm1_bt_bias(
    const void* __restrict__ A, const void* __restrict__ Bw,
    const void* __restrict__ bias, void* out, void* ws,
    const void* __restrict__ curv, int M, int N, int K)
{
  __shared__ __align__(16) u16 As[128 * 32];
  __shared__ __align__(16) u16 Bs[128 * 32];

  const bool f32 = sniff_f32(curv);
  u16* C = f32 ? (u16*)ws : (u16*)out;

  const int t = threadIdx.x;
  const int lane = t & 63;
  const int w = t >> 6;
  const int waveM = w >> 1, waveN = w & 1;
  const int m0 = blockIdx.y * 128;
  const int n0 = blockIdx.x * 128;

  floatx4 acc[4][4];
#pragma unroll
  for (int i = 0; i < 4; i++)
#pragma unroll
    for (int j = 0; j < 4; j++) {
      acc[i][j][0] = 0.f; acc[i][j][1] = 0.f;
      acc[i][j][2] = 0.f; acc[i][j][3] = 0.f;
    }

  const int r0 = t >> 2;
  const int c0 = (t & 3) * 8;
  const size_t oa0 = (size_t)(m0 + r0) * K + c0;
  const size_t oa1 = (size_t)(m0 + 64 + r0) * K + c0;
  const size_t ob0 = (size_t)(n0 + r0) * K + c0;
  const size_t ob1 = (size_t)(n0 + 64 + r0) * K + c0;

  for (int k0 = 0; k0 < K; k0 += 32) {
    uint4 a0 = load8bf(A, oa0 + k0, f32);
    uint4 a1 = load8bf(A, oa1 + k0, f32);
    uint4 b0 = load8bf(Bw, ob0 + k0, f32);
    uint4 b1 = load8bf(Bw, ob1 + k0, f32);
    __syncthreads();
    *(uint4*)(As + t * 8) = a0;
    *(uint4*)(As + 2048 + t * 8) = a1;
    *(uint4*)(Bs + t * 8) = b0;
    *(uint4*)(Bs + 2048 + t * 8) = b1;
    __syncthreads();

    bf16x8 af[4], bfr[4];
    const int am = waveM * 64 + (lane & 15);
    const int bn = waveN * 64 + (lane & 15);
    const int kq = (lane >> 4) * 8;
#pragma unroll
    for (int mt = 0; mt < 4; mt++)
      af[mt] = *(const bf16x8*)(As + (am + mt * 16) * 32 + kq);
#pragma unroll
    for (int nt = 0; nt < 4; nt++)
      bfr[nt] = *(const bf16x8*)(Bs + (bn + nt * 16) * 32 + kq);
#pragma unroll
    for (int mt = 0; mt < 4; mt++)
#pragma unroll
      for (int nt = 0; nt < 4; nt++)
        acc[mt][nt] = __builtin_amdgcn_mfma_f32_16x16x32_bf16(af[mt], bfr[nt], acc[mt][nt], 0, 0, 0);
  }

  const int quad = lane >> 4;
  const int cl = lane & 15;
#pragma unroll
  for (int mt = 0; mt < 4; mt++)
#pragma unroll
    for (int nt = 0; nt < 4; nt++) {
      const int col = n0 + waveN * 64 + nt * 16 + cl;
      const float bs = f32 ? ((const float*)bias)[col] : bf2f(((const u16*)bias)[col]);
#pragma unroll
      for (int r = 0; r < 4; r++) {
        const int row = m0 + waveM * 64 + mt * 16 + quad * 4 + r;
        C[(size_t)row * N + col] = f2bf(acc[mt][nt][r] + bs);
      }
    }
}

__global__ __launch_bounds__(256) void gemm2_fullN(
    const void* __restrict__ Bw, const void* __restrict__ bias,
    void* out, void* ws, const void* __restrict__ curv,
    int M, int N, int K)
{
  __shared__ __align__(16) u16 As[32 * 32];
  __shared__ __align__(16) u16 Bs[512 * 32];

  const bool f32 = sniff_f32(curv);
  const u16* A = f32 ? (const u16*)ws : (const u16*)out;

  const int t = threadIdx.x;
  const int lane = t & 63;
  const int w = t >> 6;
  const int m0 = blockIdx.x * 32;

  floatx4 acc[2][8];
#pragma unroll
  for (int i = 0; i < 2; i++)
#pragma unroll
    for (int j = 0; j < 8; j++) {
      acc[i][j][0] = 0.f; acc[i][j][1] = 0.f;
      acc[i][j][2] = 0.f; acc[i][j][3] = 0.f;
    }

  const int r0 = t >> 2;
  const int c0 = (t & 3) * 8;

  for (int k0 = 0; k0 < K; k0 += 32) {
    uint4 av = make_uint4(0, 0, 0, 0);
    if (t < 128)
      av = *(const uint4*)(A + (size_t)(m0 + r0) * K + k0 + c0);
    uint4 bv[8];
#pragma unroll
    for (int q = 0; q < 8; q++)
      bv[q] = load8bf(Bw, (size_t)(q * 64 + r0) * K + k0 + c0, f32);
    __syncthreads();
    if (t < 128) *(uint4*)(As + t * 8) = av;
#pragma unroll
    for (int q = 0; q < 8; q++)
      *(uint4*)(Bs + q * 2048 + t * 8) = bv[q];
    __syncthreads();

    bf16x8 af[2], bfr[8];
    const int ml = lane & 15;
    const int kq = (lane >> 4) * 8;
#pragma unroll
    for (int mt = 0; mt < 2; mt++)
      af[mt] = *(const bf16x8*)(As + (mt * 16 + ml) * 32 + kq);
#pragma unroll
    for (int nt = 0; nt < 8; nt++)
      bfr[nt] = *(const bf16x8*)(Bs + (w * 128 + nt * 16 + ml) * 32 + kq);
#pragma unroll
    for (int mt = 0; mt < 2; mt++)
#pragma unroll
      for (int nt = 0; nt < 8; nt++)
        acc[mt][nt] = __builtin_amdgcn_mfma_f32_16x16x32_bf16(af[mt], bfr[nt], acc[mt][nt], 0, 0, 0);
  }

  const int quad = lane >> 4;
  const int cl = lane & 15;
#pragma unroll
  for (int mt = 0; mt < 2; mt++)
#pragma unroll
    for (int nt = 0; nt < 8; nt++) {
      const int col = w * 128 + nt * 16 + cl;
      const float bs = f32 ? ((const float*)bias)[col] : bf2f(((const u16*)bias)[col]);
#pragma unroll
      for (int r = 0; r < 4; r++) {
        const int row = m0 + mt * 16 + quad * 4 + r;
        const float v = acc[mt][nt][r] + bs;
        if (f32) ((float*)out)[(size_t)row * N + col] = v;
        else     ((u16*)out)[(size_t)row * N + col] = f2bf(v);
      }
    }
}

// ======================= launch =======================
extern "C" void kernel_launch(void* const* d_in, const int* in_sizes, int n_in,
                              void* d_out, int out_size, void* d_ws, size_t ws_size,
                              hipStream_t stream) {
  const void* nf = d_in[0];
  const void* curv = d_in[1];
  const void* to_w = d_in[2];
  const void* to_b = d_in[3];
  const void* fr_w = d_in[4];
  const void* fr_b = d_in[5];
  const void* mw = d_in[6];

  const int M = 8192 * 9, N = 512, K = 512;
  const size_t XB = (size_t)M * N * 2;       // 75,497,472 B  bf16 intermediate / A-copy
  const size_t WWB = (size_t)512 * 512 * 2;  // one 512x512 bf16 weight matrix

  // dtype is host-invisible (in_sizes are element counts) -> all dtype
  // decisions are device-side sniffs on curvature. Host only picks the
  // scratch LAYOUT from ws_size. d_out can host the bf16 A-copy/tw-copy
  // (dead before gemm2 writes output; untouched in bf16 case).
  u16 *xb = nullptr, *a_bf = nullptr, *tw_bf = nullptr, *fw_bf = nullptr;
  bool fast = false;
  if (ws_size >= 2 * XB + 2 * WWB) {          // everything in ws
    xb    = (u16*)d_ws;
    a_bf  = (u16*)((char*)d_ws + XB);
    tw_bf = (u16*)((char*)d_ws + 2 * XB);
    fw_bf = (u16*)((char*)d_ws + 2 * XB + WWB);
    fast = true;
  } else if (ws_size >= XB + 2 * WWB) {       // weights in ws, A-copy in d_out
    xb    = (u16*)d_ws;
    tw_bf = (u16*)((char*)d_ws + XB);
    fw_bf = (u16*)((char*)d_ws + XB + WWB);
    a_bf  = (u16*)d_out;
    fast = true;
  } else if (ws_size >= XB + WWB) {           // fw in ws, A-copy + tw in d_out
    xb    = (u16*)d_ws;
    fw_bf = (u16*)((char*)d_ws + XB);
    a_bf  = (u16*)d_out;
    tw_bf = (u16*)((char*)d_out + XB);
    fast = true;
  }

  mwnorm<<<81, 64, 0, stream>>>(mw, curv);

  if (fast) {
    cvt_kernel<<<2048, 256, 0, stream>>>((const float*)nf, (const float*)to_w,
                                         (const float*)fr_w, a_bf, tw_bf, fw_bf, curv);
    gemm_fast<0><<<dim3(N / 128, M / 128), 256, 0, stream>>>(
        nf, a_bf, to_w, tw_bf, to_b, xb, curv, M, N, K);
    mobius3<<<8192, 256, 0, stream>>>(xb, xb, mw, curv);
    gemm_fast<1><<<dim3(N / 128, M / 128), 256, 0, stream>>>(
        xb, xb, fr_w, fw_bf, fr_b, d_out, curv, M, N, K);
  } else {
    // fallback: previous session's verified path
    gemm1_bt_bias<<<dim3(N / 128, M / 128), 256, 0, stream>>>(nf, to_w, to_b, d_out, d_ws, curv, M, N, K);
    mobius3<<<8192, 256, 0, stream>>>((u16*)d_ws, (u16*)d_out, mw, curv);
    gemm2_fullN<<<M / 32, 256, 0, stream>>>(fr_w, fr_b, d_out, d_ws, curv, M, N, K);
  }
}

// Round 4
// 454.249 us; speedup vs baseline: 1.4867x; 1.0434x over previous
//
#include <hip/hip_runtime.h>

typedef unsigned short u16;
typedef unsigned int u32;
typedef __bf16 bf16x8 __attribute__((ext_vector_type(8)));
typedef float floatx4 __attribute__((ext_vector_type(4)));

#define EPSF 1e-8f

// mw-edge squared norms, computed on-device each launch (batch-independent).
__device__ float g_nrm[81];

__device__ __forceinline__ float bf2f(u16 u) { return __uint_as_float(((u32)u) << 16); }
__device__ __forceinline__ u16 f2bf(float f) {
  u32 u = __float_as_uint(f);
  u += 0x7fffu + ((u >> 16) & 1u);
  return (u16)(u >> 16);
}
__device__ __forceinline__ void unpack2(u32 u, float& a, float& b) {
  a = __uint_as_float(u << 16);
  b = __uint_as_float(u & 0xffff0000u);
}
__device__ __forceinline__ float wave_sum(float s) {
#pragma unroll
  for (int m = 32; m; m >>= 1) s += __shfl_xor(s, m, 64);
  return s;
}
// packed RNE f32->bf16 (v_cvt_pk_bf16_f32)
__device__ __forceinline__ u32 cvtpk(float lo, float hi) {
  u32 r;
  asm("v_cvt_pk_bf16_f32 %0, %1, %2" : "=v"(r) : "v"(lo), "v"(hi));
  return r;
}
// 1-ULP reciprocal (v_rcp_f32) — avoids the ~10-instr IEEE divide expansion.
__device__ __forceinline__ float rcp(float x) { return __builtin_amdgcn_rcpf(x); }
// tanh for x >= 0 via v_exp_f32: tanh(x) = 1 - 2/(2^(2*log2e*x)+1).
// Saturates to 1 at inf (rcp(inf)=0), exact 0 at 0.
__device__ __forceinline__ float tanh_pos(float x) {
  float e = __builtin_amdgcn_exp2f(x * 2.885390081777927f);
  return __builtin_fmaf(-2.f, rcp(e + 1.f), 1.f);
}

typedef __attribute__((address_space(1))) void gv_t;
typedef __attribute__((address_space(3))) void lv_t;
__device__ __forceinline__ void gload_lds16(const u16* g, u16* l) {
  __builtin_amdgcn_global_load_lds((const gv_t*)g, (lv_t*)l, 16, 0, 0);
}

// Device-side dtype sniff: curvature == -1.0 always.
// f32 -1.0 = 0xBF800000 -> first u16 is 0x0000; bf16 -1.0 -> 0xBF80.
__device__ __forceinline__ bool sniff_f32(const void* curv) {
  return ((const u16*)curv)[0] == 0;
}
__device__ __forceinline__ uint4 load8bf(const void* base, size_t off, bool isf32) {
  if (!isf32) return *(const uint4*)((const u16*)base + off);
  const float* p = (const float*)base + off;
  float4 a = *(const float4*)p;
  float4 b = *(const float4*)(p + 4);
  uint4 r;
  r.x = (u32)f2bf(a.x) | ((u32)f2bf(a.y) << 16);
  r.y = (u32)f2bf(a.z) | ((u32)f2bf(a.w) << 16);
  r.z = (u32)f2bf(b.x) | ((u32)f2bf(b.y) << 16);
  r.w = (u32)f2bf(b.z) | ((u32)f2bf(b.w) << 16);
  return r;
}
__device__ __forceinline__ void load8f(const void* base, size_t off, bool isf32, float* o) {
  if (isf32) {
    const float* p = (const float*)base + off;
    float4 a = *(const float4*)p;
    float4 b = *(const float4*)(p + 4);
    o[0] = a.x; o[1] = a.y; o[2] = a.z; o[3] = a.w;
    o[4] = b.x; o[5] = b.y; o[6] = b.z; o[7] = b.w;
  } else {
    const u16* p = (const u16*)base + off;
    uint4 r = *(const uint4*)p;
    unpack2(r.x, o[0], o[1]);
    unpack2(r.y, o[2], o[3]);
    unpack2(r.z, o[4], o[5]);
    unpack2(r.w, o[6], o[7]);
  }
}

// ---------- mw norms: g_nrm[i*9+j] = ||mw[i][j]||^2 (batch-independent) ----------
__global__ __launch_bounds__(64) void mwnorm(const void* __restrict__ MW,
                                             const void* __restrict__ curv) {
  const bool f32 = sniff_f32(curv);
  const int e = blockIdx.x;       // 0..80
  const int lane = threadIdx.x;   // 0..63
  float y[8];
  load8f(MW, (size_t)e * 512 + lane * 8, f32, y);
  float s = 0.f;
#pragma unroll
  for (int p = 0; p < 8; p++) s += y[p] * y[p];
  s = wave_sum(s);
  if (lane == 0) g_nrm[e] = s;
}

// ---------- convert kernel: f32 -> bf16 for node_features, to_w, from_w ----------
__global__ __launch_bounds__(256) void cvt_kernel(
    const float* __restrict__ A, const float* __restrict__ TW, const float* __restrict__ FW,
    u16* __restrict__ oA, u16* __restrict__ oTW, u16* __restrict__ oFW,
    const void* __restrict__ curv)
{
  if (!sniff_f32(curv)) return;
  const long CA = 37748736L / 8;
  const long CW = 262144L / 8;
  const long total = CA + 2 * CW;
  for (long i = (long)blockIdx.x * blockDim.x + threadIdx.x; i < total;
       i += (long)gridDim.x * blockDim.x) {
    const float* s; u16* d; long j;
    if (i < CA)           { s = A;  d = oA;  j = i; }
    else if (i < CA + CW) { s = TW; d = oTW; j = i - CA; }
    else                  { s = FW; d = oFW; j = i - CA - CW; }
    float4 a = *(const float4*)(s + j * 8);
    float4 b = *(const float4*)(s + j * 8 + 4);
    uint4 o;
    o.x = cvtpk(a.x, a.y);
    o.y = cvtpk(a.z, a.w);
    o.z = cvtpk(b.x, b.y);
    o.w = cvtpk(b.z, b.w);
    *(uint4*)(d + j * 8) = o;
  }
}

// ---------- unified bf16 GEMM: C[M,N] = A[M,K] @ B[N,K]^T + bias ----------
// 128x128x32 tiles, global_load_lds width-16 staging. XCD-swizzled block map.
template <int FINAL>
__global__ __launch_bounds__(256) void gemm_fast(
    const void* __restrict__ origA, const u16* __restrict__ convA,
    const void* __restrict__ origB, const u16* __restrict__ convB,
    const void* __restrict__ bias, void* __restrict__ out,
    const void* __restrict__ curv, int M, int N, int K)
{
  __shared__ __align__(16) u16 As[128 * 32];
  __shared__ __align__(16) u16 Bs[128 * 32];

  const bool f32 = sniff_f32(curv);
  const u16* A = f32 ? convA : (const u16*)origA;
  const u16* B = f32 ? convB : (const u16*)origB;

  const int t = threadIdx.x;
  const int lane = t & 63;
  const int w = t >> 6;
  const int waveM = w >> 1, waveN = w & 1;

  // XCD-aware bijective swizzle: contiguous logical-tile chunk per XCD.
  int lid = blockIdx.x + blockIdx.y * gridDim.x;
  const int nwg = gridDim.x * gridDim.y;
  if ((nwg & 7) == 0) lid = (lid & 7) * (nwg >> 3) + (lid >> 3);
  const int m0 = (lid / gridDim.x) * 128;
  const int n0 = (lid % gridDim.x) * 128;

  floatx4 acc[4][4];
#pragma unroll
  for (int i = 0; i < 4; i++)
#pragma unroll
    for (int j = 0; j < 4; j++) {
      acc[i][j][0] = 0.f; acc[i][j][1] = 0.f;
      acc[i][j][2] = 0.f; acc[i][j][3] = 0.f;
    }

  const u16* ga0 = A + (size_t)(m0 + (t >> 2)) * K + (t & 3) * 8;
  const u16* ga1 = ga0 + (size_t)64 * K;
  const u16* gb0 = B + (size_t)(n0 + (t >> 2)) * K + (t & 3) * 8;
  const u16* gb1 = gb0 + (size_t)64 * K;
  u16* lA0 = As + w * 512;
  u16* lA1 = As + 2048 + w * 512;
  u16* lB0 = Bs + w * 512;
  u16* lB1 = Bs + 2048 + w * 512;

  const int am = waveM * 64 + (lane & 15);
  const int bn = waveN * 64 + (lane & 15);
  const int kq = (lane >> 4) * 8;

  for (int k0 = 0; k0 < K; k0 += 32) {
    gload_lds16(ga0 + k0, lA0);
    gload_lds16(ga1 + k0, lA1);
    gload_lds16(gb0 + k0, lB0);
    gload_lds16(gb1 + k0, lB1);
    __syncthreads();

    bf16x8 af[4], bfr[4];
#pragma unroll
    for (int mt = 0; mt < 4; mt++)
      af[mt] = *(const bf16x8*)(As + (am + mt * 16) * 32 + kq);
#pragma unroll
    for (int nt = 0; nt < 4; nt++)
      bfr[nt] = *(const bf16x8*)(Bs + (bn + nt * 16) * 32 + kq);
#pragma unroll
    for (int mt = 0; mt < 4; mt++)
#pragma unroll
      for (int nt = 0; nt < 4; nt++)
        acc[mt][nt] = __builtin_amdgcn_mfma_f32_16x16x32_bf16(af[mt], bfr[nt], acc[mt][nt], 0, 0, 0);
    __syncthreads();
  }

  const int quad = lane >> 4;
  const int cl = lane & 15;
#pragma unroll
  for (int mt = 0; mt < 4; mt++)
#pragma unroll
    for (int nt = 0; nt < 4; nt++) {
      const int col = n0 + waveN * 64 + nt * 16 + cl;
      const float bs = f32 ? ((const float*)bias)[col] : bf2f(((const u16*)bias)[col]);
#pragma unroll
      for (int r = 0; r < 4; r++) {
        const int row = m0 + waveM * 64 + mt * 16 + quad * 4 + r;
        const float v = acc[mt][nt][r] + bs;
        if (FINAL && f32) ((float*)out)[(size_t)row * N + col] = v;
        else              ((u16*)out)[(size_t)row * N + col] = f2bf(v);
      }
    }
}

// ---------- Mobius v4: z-folded algebra + rcp + exp2-tanh. ----------
// Per edge: ONE combined vector z = a1*x + b1*y replaces the (x,y) pair:
//   t  = inv1*z,  rt = inv1*<r,z>,  tt = inv1^2*(a1^2 xx + 2 a1 b1 xy + b1^2 yy)
//   r' = ca*r + (cb*inv1)*z,  rr' = inv2^2*(a2^2 rr + 2 a2 b2 rt + b2^2 tt)
// -> 2 wave reductions per edge (xy, rz) instead of 3; 2-op/elem update.
// All divides are v_rcp_f32; tanh via v_exp_f32.
__global__ __launch_bounds__(256) void mobius4(
    u16* Xf, u16* Xb, const void* __restrict__ MW, const void* __restrict__ curv)
{
  __shared__ float h[9][512];
  __shared__ float hh[9];    // ||h_i||^2
  __shared__ float chh[9];   // c*||h_i||^2
  __shared__ float b1n[9];   // 1 - c*||h_i||^2

  const bool f32 = sniff_f32(curv);
  u16* X = f32 ? Xf : Xb;

  const int b = blockIdx.x;
  const int t = threadIdx.x;
  const int lane = t & 63;
  const int w = t >> 6;
  const float c = f32 ? fabsf(((const float*)curv)[0]) : fabsf(bf2f(((const u16*)curv)[0]));
  const float c2 = 2.f * c;

  for (int r = w; r < 9; r += 4) {
    uint4 raw = *(const uint4*)(X + ((size_t)b * 9 + r) * 512 + lane * 8);
    float x[8];
    unpack2(raw.x, x[0], x[1]);
    unpack2(raw.y, x[2], x[3]);
    unpack2(raw.z, x[4], x[5]);
    unpack2(raw.w, x[6], x[7]);
    float s = 0.f;
#pragma unroll
    for (int p = 0; p < 8; p++) s += x[p] * x[p];
    s = wave_sum(s);
    const float norm = sqrtf(s);
    const float scale = tanh_pos(norm) * rcp(norm + EPSF);
#pragma unroll
    for (int p = 0; p < 8; p++) h[r][lane * 8 + p] = x[p] * scale;
    if (lane == 0) {
      const float q = scale * scale * s;
      hh[r] = q;
      chh[r] = c * q;
      b1n[r] = 1.f - c * q;
    }
  }
  __syncthreads();

  const int baseNode[4] = {8, 0, 3, 6};
  const int cntNode[4] = {1, 3, 3, 2};
  const int nbrCnt[9] = {3, 3, 2, 3, 3, 2, 3, 3, 8};
  const int nbrTab[9][8] = {
      {4, 7, 8, 0, 0, 0, 0, 0}, {0, 6, 8, 0, 0, 0, 0, 0}, {5, 8, 0, 0, 0, 0, 0, 0},
      {1, 4, 8, 0, 0, 0, 0, 0}, {6, 3, 8, 0, 0, 0, 0, 0}, {2, 8, 0, 0, 0, 0, 0, 0},
      {7, 1, 8, 0, 0, 0, 0, 0}, {3, 0, 8, 0, 0, 0, 0, 0}, {0, 1, 2, 3, 4, 5, 6, 7}};

  for (int s = 0; s < cntNode[w]; s++) {
    const int i = baseNode[w] + s;
    float r8[8];
#pragma unroll
    for (int p = 0; p < 8; p++) r8[p] = h[i][lane * 8 + p];
    float rr = hh[i];  // ||r||^2 initial

    for (int e = 0; e < nbrCnt[i]; e++) {
      const int j = nbrTab[i][e];
      float y[8];
      load8f(MW, ((size_t)i * 9 + j) * 512 + lane * 8, f32, y);
      float x8[8];
#pragma unroll
      for (int p = 0; p < 8; p++) x8[p] = h[j][lane * 8 + p];

      // reduction 1: xy = <x, y>
      float xy = 0.f;
#pragma unroll
      for (int p = 0; p < 8; p++) xy = __builtin_fmaf(x8[p], y[p], xy);
      xy = wave_sum(xy);

      const float xx = hh[j];
      const float yy = g_nrm[i * 9 + j];
      const float cyy = c * yy;
      const float a1 = __builtin_fmaf(c2, xy, 1.f + cyy);
      const float b1 = b1n[j];
      const float d1 = __builtin_fmaf(chh[j], cyy, 1.f + EPSF);
      const float inv1 = rcp(__builtin_fmaf(c2, xy, d1));

      // z = a1*x + b1*y  (t = inv1*z, never materialized)
      float z8[8];
#pragma unroll
      for (int p = 0; p < 8; p++) z8[p] = __builtin_fmaf(a1, x8[p], b1 * y[p]);

      // reduction 2: rz = <r, z>
      float rz = 0.f;
#pragma unroll
      for (int p = 0; p < 8; p++) rz = __builtin_fmaf(r8[p], z8[p], rz);
      rz = wave_sum(rz);

      const float rt = inv1 * rz;
      const float a1b1 = a1 * b1;
      const float inv1sq = inv1 * inv1;
      float ttn = __builtin_fmaf(b1 * b1, yy, __builtin_fmaf(a1b1 + a1b1, xy, a1 * a1 * xx));
      const float tt = ttn * inv1sq;

      const float ctt = c * tt;
      const float crr = c * rr;
      const float a2 = __builtin_fmaf(c2, rt, 1.f + ctt);
      const float b2 = 1.f - crr;
      const float d2 = __builtin_fmaf(crr, ctt, 1.f + EPSF);
      const float inv2 = rcp(__builtin_fmaf(c2, rt, d2));
      const float ca = a2 * inv2;
      const float cz = b2 * inv2 * inv1;
#pragma unroll
      for (int p = 0; p < 8; p++)
        r8[p] = __builtin_fmaf(ca, r8[p], cz * z8[p]);
      const float a2b2 = a2 * b2;
      const float inv2sq = inv2 * inv2;
      rr = inv2sq * __builtin_fmaf(b2 * b2, tt,
                    __builtin_fmaf(a2b2 + a2b2, rt, a2 * a2 * rr));
    }

    uint4 o;
    o.x = cvtpk(r8[0], r8[1]);
    o.y = cvtpk(r8[2], r8[3]);
    o.z = cvtpk(r8[4], r8[5]);
    o.w = cvtpk(r8[6], r8[7]);
    *(uint4*)(X + ((size_t)b * 9 + i) * 512 + lane * 8) = o;
  }
}

// ================= FALLBACK PATH (previous session's verified kernels) =================
__global__ __launch_bounds__(256) void gemm1_bt_bias(
    const void* __restrict__ A, const void* __restrict__ Bw,
    const void* __restrict__ bias, void* out, void* ws,
    const void* __restrict__ curv, int M, int N, int K)
{
  __shared__ __align__(16) u16 As[128 * 32];
  __shared__ __align__(16) u16 Bs[128 * 32];

  const bool f32 = sniff_f32(curv);
  u16* C = f32 ? (u16*)ws : (u16*)out;

  const int t = threadIdx.x;
  const int lane = t & 63;
  const int w = t >> 6;
  const int waveM = w >> 1, waveN = w & 1;
  const int m0 = blockIdx.y * 128;
  const int n0 = blockIdx.x * 128;

  floatx4 acc[4][4];
#pragma unroll
  for (int i = 0; i < 4; i++)
#pragma unroll
    for (int j = 0; j < 4; j++) {
      acc[i][j][0] = 0.f; acc[i][j][1] = 0.f;
      acc[i][j][2] = 0.f; acc[i][j][3] = 0.f;
    }

  const int r0 = t >> 2;
  const int c0 = (t & 3) * 8;
  const size_t oa0 = (size_t)(m0 + r0) * K + c0;
  const size_t oa1 = (size_t)(m0 + 64 + r0) * K + c0;
  const size_t ob0 = (size_t)(n0 + r0) * K + c0;
  const size_t ob1 = (size_t)(n0 + 64 + r0) * K + c0;

  for (int k0 = 0; k0 < K; k0 += 32) {
    uint4 a0 = load8bf(A, oa0 + k0, f32);
    uint4 a1 = load8bf(A, oa1 + k0, f32);
    uint4 b0 = load8bf(Bw, ob0 + k0, f32);
    uint4 b1 = load8bf(Bw, ob1 + k0, f32);
    __syncthreads();
    *(uint4*)(As + t * 8) = a0;
    *(uint4*)(As + 2048 + t * 8) = a1;
    *(uint4*)(Bs + t * 8) = b0;
    *(uint4*)(Bs + 2048 + t * 8) = b1;
    __syncthreads();

    bf16x8 af[4], bfr[4];
    const int am = waveM * 64 + (lane & 15);
    const int bn = waveN * 64 + (lane & 15);
    const int kq = (lane >> 4) * 8;
#pragma unroll
    for (int mt = 0; mt < 4; mt++)
      af[mt] = *(const bf16x8*)(As + (am + mt * 16) * 32 + kq);
#pragma unroll
    for (int nt = 0; nt < 4; nt++)
      bfr[nt] = *(const bf16x8*)(Bs + (bn + nt * 16) * 32 + kq);
#pragma unroll
    for (int mt = 0; mt < 4; mt++)
#pragma unroll
      for (int nt = 0; nt < 4; nt++)
        acc[mt][nt] = __builtin_amdgcn_mfma_f32_16x16x32_bf16(af[mt], bfr[nt], acc[mt][nt], 0, 0, 0);
  }

  const int quad = lane >> 4;
  const int cl = lane & 15;
#pragma unroll
  for (int mt = 0; mt < 4; mt++)
#pragma unroll
    for (int nt = 0; nt < 4; nt++) {
      const int col = n0 + waveN * 64 + nt * 16 + cl;
      const float bs = f32 ? ((const float*)bias)[col] : bf2f(((const u16*)bias)[col]);
#pragma unroll
      for (int r = 0; r < 4; r++) {
        const int row = m0 + waveM * 64 + mt * 16 + quad * 4 + r;
        C[(size_t)row * N + col] = f2bf(acc[mt][nt][r] + bs);
      }
    }
}

__global__ __launch_bounds__(256) void gemm2_fullN(
    const void* __restrict__ Bw, const void* __restrict__ bias,
    void* out, void* ws, const void* __restrict__ curv,
    int M, int N, int K)
{
  __shared__ __align__(16) u16 As[32 * 32];
  __shared__ __align__(16) u16 Bs[512 * 32];

  const bool f32 = sniff_f32(curv);
  const u16* A = f32 ? (const u16*)ws : (const u16*)out;

  const int t = threadIdx.x;
  const int lane = t & 63;
  const int w = t >> 6;
  const int m0 = blockIdx.x * 32;

  floatx4 acc[2][8];
#pragma unroll
  for (int i = 0; i < 2; i++)
#pragma unroll
    for (int j = 0; j < 8; j++) {
      acc[i][j][0] = 0.f; acc[i][j][1] = 0.f;
      acc[i][j][2] = 0.f; acc[i][j][3] = 0.f;
    }

  const int r0 = t >> 2;
  const int c0 = (t & 3) * 8;

  for (int k0 = 0; k0 < K; k0 += 32) {
    uint4 av = make_uint4(0, 0, 0, 0);
    if (t < 128)
      av = *(const uint4*)(A + (size_t)(m0 + r0) * K + k0 + c0);
    uint4 bv[8];
#pragma unroll
    for (int q = 0; q < 8; q++)
      bv[q] = load8bf(Bw, (size_t)(q * 64 + r0) * K + k0 + c0, f32);
    __syncthreads();
    if (t < 128) *(uint4*)(As + t * 8) = av;
#pragma unroll
    for (int q = 0; q < 8; q++)
      *(uint4*)(Bs + q * 2048 + t * 8) = bv[q];
    __syncthreads();

    bf16x8 af[2], bfr[8];
    const int ml = lane & 15;
    const int kq = (lane >> 4) * 8;
#pragma unroll
    for (int mt = 0; mt < 2; mt++)
      af[mt] = *(const bf16x8*)(As + (mt * 16 + ml) * 32 + kq);
#pragma unroll
    for (int nt = 0; nt < 8; nt++)
      bfr[nt] = *(const bf16x8*)(Bs + (w * 128 + nt * 16 + ml) * 32 + kq);
#pragma unroll
    for (int mt = 0; mt < 2; mt++)
#pragma unroll
      for (int nt = 0; nt < 8; nt++)
        acc[mt][nt] = __builtin_amdgcn_mfma_f32_16x16x32_bf16(af[mt], bfr[nt], acc[mt][nt], 0, 0, 0);
  }

  const int quad = lane >> 4;
  const int cl = lane & 15;
#pragma unroll
  for (int mt = 0; mt < 2; mt++)
#pragma unroll
    for (int nt = 0; nt < 8; nt++) {
      const int col = w * 128 + nt * 16 + cl;
      const float bs = f32 ? ((const float*)bias)[col] : bf2f(((const u16*)bias)[col]);
#pragma unroll
      for (int r = 0; r < 4; r++) {
        const int row = m0 + mt * 16 + quad * 4 + r;
        const float v = acc[mt][nt][r] + bs;
        if (f32) ((float*)out)[(size_t)row * N + col] = v;
        else     ((u16*)out)[(size_t)row * N + col] = f2bf(v);
      }
    }
}

// ======================= launch =======================
extern "C" void kernel_launch(void* const* d_in, const int* in_sizes, int n_in,
                              void* d_out, int out_size, void* d_ws, size_t ws_size,
                              hipStream_t stream) {
  const void* nf = d_in[0];
  const void* curv = d_in[1];
  const void* to_w = d_in[2];
  const void* to_b = d_in[3];
  const void* fr_w = d_in[4];
  const void* fr_b = d_in[5];
  const void* mw = d_in[6];

  const int M = 8192 * 9, N = 512, K = 512;
  const size_t XB = (size_t)M * N * 2;       // 75,497,472 B  bf16 intermediate / A-copy
  const size_t WWB = (size_t)512 * 512 * 2;  // one 512x512 bf16 weight matrix

  // dtype is host-invisible (in_sizes are element counts) -> all dtype
  // decisions are device-side sniffs on curvature. Host only picks the
  // scratch LAYOUT from ws_size.
  u16 *xb = nullptr, *a_bf = nullptr, *tw_bf = nullptr, *fw_bf = nullptr;
  bool fast = false;
  if (ws_size >= 2 * XB + 2 * WWB) {          // everything in ws
    xb    = (u16*)d_ws;
    a_bf  = (u16*)((char*)d_ws + XB);
    tw_bf = (u16*)((char*)d_ws + 2 * XB);
    fw_bf = (u16*)((char*)d_ws + 2 * XB + WWB);
    fast = true;
  } else if (ws_size >= XB + 2 * WWB) {       // weights in ws, A-copy in d_out
    xb    = (u16*)d_ws;
    tw_bf = (u16*)((char*)d_ws + XB);
    fw_bf = (u16*)((char*)d_ws + XB + WWB);
    a_bf  = (u16*)d_out;
    fast = true;
  } else if (ws_size >= XB + WWB) {           // fw in ws, A-copy + tw in d_out
    xb    = (u16*)d_ws;
    fw_bf = (u16*)((char*)d_ws + XB);
    a_bf  = (u16*)d_out;
    tw_bf = (u16*)((char*)d_out + XB);
    fast = true;
  }

  mwnorm<<<81, 64, 0, stream>>>(mw, curv);

  if (fast) {
    cvt_kernel<<<2048, 256, 0, stream>>>((const float*)nf, (const float*)to_w,
                                         (const float*)fr_w, a_bf, tw_bf, fw_bf, curv);
    gemm_fast<0><<<dim3(N / 128, M / 128), 256, 0, stream>>>(
        nf, a_bf, to_w, tw_bf, to_b, xb, curv, M, N, K);
    mobius4<<<8192, 256, 0, stream>>>(xb, xb, mw, curv);
    gemm_fast<1><<<dim3(N / 128, M / 128), 256, 0, stream>>>(
        xb, xb, fr_w, fw_bf, fr_b, d_out, curv, M, N, K);
  } else {
    // fallback: previous session's verified path
    gemm1_bt_bias<<<dim3(N / 128, M / 128), 256, 0, stream>>>(nf, to_w, to_b, d_out, d_ws, curv, M, N, K);
    mobius4<<<8192, 256, 0, stream>>>((u16*)d_ws, (u16*)d_out, mw, curv);
    gemm2_fullN<<<M / 32, 256, 0, stream>>>(fr_w, fr_b, d_out, d_ws, curv, M, N, K);
  }
}

// Round 5
// 443.589 us; speedup vs baseline: 1.5224x; 1.0240x over previous
//
#include <hip/hip_runtime.h>

typedef unsigned short u16;
typedef unsigned int u32;
typedef __bf16 bf16x8 __attribute__((ext_vector_type(8)));
typedef float floatx4 __attribute__((ext_vector_type(4)));

#define EPSF 1e-8f

// mw-edge squared norms, computed on-device each launch (batch-independent).
__device__ float g_nrm[81];

__device__ __forceinline__ float bf2f(u16 u) { return __uint_as_float(((u32)u) << 16); }
__device__ __forceinline__ u16 f2bf(float f) {
  u32 u = __float_as_uint(f);
  u += 0x7fffu + ((u >> 16) & 1u);
  return (u16)(u >> 16);
}
__device__ __forceinline__ void unpack2(u32 u, float& a, float& b) {
  a = __uint_as_float(u << 16);
  b = __uint_as_float(u & 0xffff0000u);
}
__device__ __forceinline__ float wave_sum(float s) {
#pragma unroll
  for (int m = 32; m; m >>= 1) s += __shfl_xor(s, m, 64);
  return s;
}
// packed RNE f32->bf16 (v_cvt_pk_bf16_f32)
__device__ __forceinline__ u32 cvtpk(float lo, float hi) {
  u32 r;
  asm("v_cvt_pk_bf16_f32 %0, %1, %2" : "=v"(r) : "v"(lo), "v"(hi));
  return r;
}
// 1-ULP reciprocal (v_rcp_f32)
__device__ __forceinline__ float rcp(float x) { return __builtin_amdgcn_rcpf(x); }
// tanh for x >= 0 via v_exp_f32: tanh(x) = 1 - 2/(2^(2*log2e*x)+1).
__device__ __forceinline__ float tanh_pos(float x) {
  float e = __builtin_amdgcn_exp2f(x * 2.885390081777927f);
  return __builtin_fmaf(-2.f, rcp(e + 1.f), 1.f);
}

typedef __attribute__((address_space(1))) void gv_t;
typedef __attribute__((address_space(3))) void lv_t;
__device__ __forceinline__ void gload_lds16(const u16* g, u16* l) {
  __builtin_amdgcn_global_load_lds((const gv_t*)g, (lv_t*)l, 16, 0, 0);
}

// Device-side dtype sniff: curvature == -1.0 always.
// f32 -1.0 = 0xBF800000 -> first u16 is 0x0000; bf16 -1.0 -> 0xBF80.
__device__ __forceinline__ bool sniff_f32(const void* curv) {
  return ((const u16*)curv)[0] == 0;
}
__device__ __forceinline__ uint4 load8bf(const void* base, size_t off, bool isf32) {
  if (!isf32) return *(const uint4*)((const u16*)base + off);
  const float* p = (const float*)base + off;
  float4 a = *(const float4*)p;
  float4 b = *(const float4*)(p + 4);
  uint4 r;
  r.x = (u32)f2bf(a.x) | ((u32)f2bf(a.y) << 16);
  r.y = (u32)f2bf(a.z) | ((u32)f2bf(a.w) << 16);
  r.z = (u32)f2bf(b.x) | ((u32)f2bf(b.y) << 16);
  r.w = (u32)f2bf(b.z) | ((u32)f2bf(b.w) << 16);
  return r;
}
__device__ __forceinline__ void load8f(const void* base, size_t off, bool isf32, float* o) {
  if (isf32) {
    const float* p = (const float*)base + off;
    float4 a = *(const float4*)p;
    float4 b = *(const float4*)(p + 4);
    o[0] = a.x; o[1] = a.y; o[2] = a.z; o[3] = a.w;
    o[4] = b.x; o[5] = b.y; o[6] = b.z; o[7] = b.w;
  } else {
    const u16* p = (const u16*)base + off;
    uint4 r = *(const uint4*)p;
    unpack2(r.x, o[0], o[1]);
    unpack2(r.y, o[2], o[3]);
    unpack2(r.z, o[4], o[5]);
    unpack2(r.w, o[6], o[7]);
  }
}

// ---------- mw norms: g_nrm[i*9+j] = ||mw[i][j]||^2 (batch-independent) ----------
__global__ __launch_bounds__(64) void mwnorm(const void* __restrict__ MW,
                                             const void* __restrict__ curv) {
  const bool f32 = sniff_f32(curv);
  const int e = blockIdx.x;       // 0..80
  const int lane = threadIdx.x;   // 0..63
  float y[8];
  load8f(MW, (size_t)e * 512 + lane * 8, f32, y);
  float s = 0.f;
#pragma unroll
  for (int p = 0; p < 8; p++) s += y[p] * y[p];
  s = wave_sum(s);
  if (lane == 0) g_nrm[e] = s;
}

// ---------- weight convert: f32 -> bf16 for to_w, from_w (A is fused into gemm1) ----------
__global__ __launch_bounds__(256) void cvt_w(
    const float* __restrict__ TW, const float* __restrict__ FW,
    u16* __restrict__ oTW, u16* __restrict__ oFW, const void* __restrict__ curv)
{
  if (!sniff_f32(curv)) return;
  const int i = blockIdx.x * 256 + threadIdx.x;  // 65536 threads x 8 elems = 2x512x512
  const bool first = i < 32768;
  const float* s = first ? TW : FW;
  u16* d = first ? oTW : oFW;
  const long j = first ? i : i - 32768;
  float4 a = *(const float4*)(s + j * 8);
  float4 b = *(const float4*)(s + j * 8 + 4);
  uint4 o;
  o.x = cvtpk(a.x, a.y);
  o.y = cvtpk(a.z, a.w);
  o.z = cvtpk(b.x, b.y);
  o.w = cvtpk(b.z, b.w);
  *(uint4*)(d + j * 8) = o;
}

// ---------- unified bf16 GEMM: C[M,N] = A[M,K] @ B[N,K]^T + bias ----------
// 128x128x32 tiles. B staged via global_load_lds width-16. A staged either via
// global_load_lds (bf16 source) or reg-stage f32->cvt_pk->ds_write (CONVA=1 &
// f32 inputs) — this fuses the A dtype conversion into the GEMM, deleting the
// separate 226MB convert pass. XCD-swizzled block map.
// FINAL=1: store f32 when inputs f32, else bf16.
template <int FINAL, int CONVA>
__global__ __launch_bounds__(256) void gemm_fast(
    const void* __restrict__ origA, const u16* __restrict__ convA,
    const void* __restrict__ origB, const u16* __restrict__ convB,
    const void* __restrict__ bias, void* __restrict__ out,
    const void* __restrict__ curv, int M, int N, int K)
{
  __shared__ __align__(16) u16 As[128 * 32];
  __shared__ __align__(16) u16 Bs[128 * 32];

  const bool f32 = sniff_f32(curv);
  const bool stageA32 = CONVA && f32;              // convert A inline from f32
  const u16* A = f32 ? convA : (const u16*)origA;  // bf16 A base (unused if stageA32)
  const u16* B = f32 ? convB : (const u16*)origB;
  const float* Af = (const float*)origA;

  const int t = threadIdx.x;
  const int lane = t & 63;
  const int w = t >> 6;
  const int waveM = w >> 1, waveN = w & 1;

  // XCD-aware bijective swizzle: contiguous logical-tile chunk per XCD.
  int lid = blockIdx.x + blockIdx.y * gridDim.x;
  const int nwg = gridDim.x * gridDim.y;
  if ((nwg & 7) == 0) lid = (lid & 7) * (nwg >> 3) + (lid >> 3);
  const int m0 = (lid / gridDim.x) * 128;
  const int n0 = (lid % gridDim.x) * 128;

  floatx4 acc[4][4];
#pragma unroll
  for (int i = 0; i < 4; i++)
#pragma unroll
    for (int j = 0; j < 4; j++) {
      acc[i][j][0] = 0.f; acc[i][j][1] = 0.f;
      acc[i][j][2] = 0.f; acc[i][j][3] = 0.f;
    }

  const int r0 = t >> 2;          // 0..63: row within half-tile
  const int c0 = (t & 3) * 8;     // 0/8/16/24: col
  // bf16 staging sources (A used only when !stageA32)
  const u16* ga0 = A + (size_t)(m0 + r0) * K + c0;
  const u16* ga1 = ga0 + (size_t)64 * K;
  const u16* gb0 = B + (size_t)(n0 + r0) * K + c0;
  const u16* gb1 = gb0 + (size_t)64 * K;
  // f32 staging sources (A when stageA32)
  const float* fa0 = Af + (size_t)(m0 + r0) * K + c0;
  const float* fa1 = fa0 + (size_t)64 * K;
  // LDS destinations: thread t covers byte offset t*16 of each 4KB half-tile,
  // i.e. element r0*32 + c0  (t*8 elems). global_load_lds dest = base + lane*16.
  u16* lA0 = As + w * 512;
  u16* lA1 = As + 2048 + w * 512;
  u16* lB0 = Bs + w * 512;
  u16* lB1 = Bs + 2048 + w * 512;
  u16* wA0 = As + t * 8;          // ds_write dest (same element as lA0 coverage)
  u16* wA1 = As + 2048 + t * 8;

  const int am = waveM * 64 + (lane & 15);
  const int bn = waveN * 64 + (lane & 15);
  const int kq = (lane >> 4) * 8;

  for (int k0 = 0; k0 < K; k0 += 32) {
    // issue B DMA first so it overlaps the A register round-trip
    gload_lds16(gb0 + k0, lB0);
    gload_lds16(gb1 + k0, lB1);
    if (stageA32) {
      float4 a0 = *(const float4*)(fa0 + k0);
      float4 a1 = *(const float4*)(fa0 + k0 + 4);
      float4 b0 = *(const float4*)(fa1 + k0);
      float4 b1 = *(const float4*)(fa1 + k0 + 4);
      uint4 o0, o1;
      o0.x = cvtpk(a0.x, a0.y); o0.y = cvtpk(a0.z, a0.w);
      o0.z = cvtpk(a1.x, a1.y); o0.w = cvtpk(a1.z, a1.w);
      o1.x = cvtpk(b0.x, b0.y); o1.y = cvtpk(b0.z, b0.w);
      o1.z = cvtpk(b1.x, b1.y); o1.w = cvtpk(b1.z, b1.w);
      *(uint4*)wA0 = o0;
      *(uint4*)wA1 = o1;
    } else {
      gload_lds16(ga0 + k0, lA0);
      gload_lds16(ga1 + k0, lA1);
    }
    __syncthreads();  // drains vmcnt+lgkmcnt: tile ready

    bf16x8 af[4], bfr[4];
#pragma unroll
    for (int mt = 0; mt < 4; mt++)
      af[mt] = *(const bf16x8*)(As + (am + mt * 16) * 32 + kq);
#pragma unroll
    for (int nt = 0; nt < 4; nt++)
      bfr[nt] = *(const bf16x8*)(Bs + (bn + nt * 16) * 32 + kq);
#pragma unroll
    for (int mt = 0; mt < 4; mt++)
#pragma unroll
      for (int nt = 0; nt < 4; nt++)
        acc[mt][nt] = __builtin_amdgcn_mfma_f32_16x16x32_bf16(af[mt], bfr[nt], acc[mt][nt], 0, 0, 0);
    __syncthreads();  // all reads done before next stage overwrites
  }

  const int quad = lane >> 4;
  const int cl = lane & 15;
#pragma unroll
  for (int mt = 0; mt < 4; mt++)
#pragma unroll
    for (int nt = 0; nt < 4; nt++) {
      const int col = n0 + waveN * 64 + nt * 16 + cl;
      const float bs = f32 ? ((const float*)bias)[col] : bf2f(((const u16*)bias)[col]);
#pragma unroll
      for (int r = 0; r < 4; r++) {
        const int row = m0 + waveM * 64 + mt * 16 + quad * 4 + r;
        const float v = acc[mt][nt][r] + bs;
        if (FINAL && f32) ((float*)out)[(size_t)row * N + col] = v;
        else              ((u16*)out)[(size_t)row * N + col] = f2bf(v);
      }
    }
}

// ---------- Mobius v4: z-folded algebra + rcp + exp2-tanh (verified R4). ----------
__global__ __launch_bounds__(256) void mobius4(
    u16* Xf, u16* Xb, const void* __restrict__ MW, const void* __restrict__ curv)
{
  __shared__ float h[9][512];
  __shared__ float hh[9];    // ||h_i||^2
  __shared__ float chh[9];   // c*||h_i||^2
  __shared__ float b1n[9];   // 1 - c*||h_i||^2

  const bool f32 = sniff_f32(curv);
  u16* X = f32 ? Xf : Xb;

  const int b = blockIdx.x;
  const int t = threadIdx.x;
  const int lane = t & 63;
  const int w = t >> 6;
  const float c = f32 ? fabsf(((const float*)curv)[0]) : fabsf(bf2f(((const u16*)curv)[0]));
  const float c2 = 2.f * c;

  for (int r = w; r < 9; r += 4) {
    uint4 raw = *(const uint4*)(X + ((size_t)b * 9 + r) * 512 + lane * 8);
    float x[8];
    unpack2(raw.x, x[0], x[1]);
    unpack2(raw.y, x[2], x[3]);
    unpack2(raw.z, x[4], x[5]);
    unpack2(raw.w, x[6], x[7]);
    float s = 0.f;
#pragma unroll
    for (int p = 0; p < 8; p++) s += x[p] * x[p];
    s = wave_sum(s);
    const float norm = sqrtf(s);
    const float scale = tanh_pos(norm) * rcp(norm + EPSF);
#pragma unroll
    for (int p = 0; p < 8; p++) h[r][lane * 8 + p] = x[p] * scale;
    if (lane == 0) {
      const float q = scale * scale * s;
      hh[r] = q;
      chh[r] = c * q;
      b1n[r] = 1.f - c * q;
    }
  }
  __syncthreads();

  const int baseNode[4] = {8, 0, 3, 6};
  const int cntNode[4] = {1, 3, 3, 2};
  const int nbrCnt[9] = {3, 3, 2, 3, 3, 2, 3, 3, 8};
  const int nbrTab[9][8] = {
      {4, 7, 8, 0, 0, 0, 0, 0}, {0, 6, 8, 0, 0, 0, 0, 0}, {5, 8, 0, 0, 0, 0, 0, 0},
      {1, 4, 8, 0, 0, 0, 0, 0}, {6, 3, 8, 0, 0, 0, 0, 0}, {2, 8, 0, 0, 0, 0, 0, 0},
      {7, 1, 8, 0, 0, 0, 0, 0}, {3, 0, 8, 0, 0, 0, 0, 0}, {0, 1, 2, 3, 4, 5, 6, 7}};

  for (int s = 0; s < cntNode[w]; s++) {
    const int i = baseNode[w] + s;
    float r8[8];
#pragma unroll
    for (int p = 0; p < 8; p++) r8[p] = h[i][lane * 8 + p];
    float rr = hh[i];

    for (int e = 0; e < nbrCnt[i]; e++) {
      const int j = nbrTab[i][e];
      float y[8];
      load8f(MW, ((size_t)i * 9 + j) * 512 + lane * 8, f32, y);
      float x8[8];
#pragma unroll
      for (int p = 0; p < 8; p++) x8[p] = h[j][lane * 8 + p];

      float xy = 0.f;
#pragma unroll
      for (int p = 0; p < 8; p++) xy = __builtin_fmaf(x8[p], y[p], xy);
      xy = wave_sum(xy);

      const float xx = hh[j];
      const float yy = g_nrm[i * 9 + j];
      const float cyy = c * yy;
      const float a1 = __builtin_fmaf(c2, xy, 1.f + cyy);
      const float b1 = b1n[j];
      const float d1 = __builtin_fmaf(chh[j], cyy, 1.f + EPSF);
      const float inv1 = rcp(__builtin_fmaf(c2, xy, d1));

      float z8[8];
#pragma unroll
      for (int p = 0; p < 8; p++) z8[p] = __builtin_fmaf(a1, x8[p], b1 * y[p]);

      float rz = 0.f;
#pragma unroll
      for (int p = 0; p < 8; p++) rz = __builtin_fmaf(r8[p], z8[p], rz);
      rz = wave_sum(rz);

      const float rt = inv1 * rz;
      const float a1b1 = a1 * b1;
      const float inv1sq = inv1 * inv1;
      float ttn = __builtin_fmaf(b1 * b1, yy, __builtin_fmaf(a1b1 + a1b1, xy, a1 * a1 * xx));
      const float tt = ttn * inv1sq;

      const float ctt = c * tt;
      const float crr = c * rr;
      const float a2 = __builtin_fmaf(c2, rt, 1.f + ctt);
      const float b2 = 1.f - crr;
      const float d2 = __builtin_fmaf(crr, ctt, 1.f + EPSF);
      const float inv2 = rcp(__builtin_fmaf(c2, rt, d2));
      const float ca = a2 * inv2;
      const float cz = b2 * inv2 * inv1;
#pragma unroll
      for (int p = 0; p < 8; p++)
        r8[p] = __builtin_fmaf(ca, r8[p], cz * z8[p]);
      const float a2b2 = a2 * b2;
      const float inv2sq = inv2 * inv2;
      rr = inv2sq * __builtin_fmaf(b2 * b2, tt,
                    __builtin_fmaf(a2b2 + a2b2, rt, a2 * a2 * rr));
    }

    uint4 o;
    o.x = cvtpk(r8[0], r8[1]);
    o.y = cvtpk(r8[2], r8[3]);
    o.z = cvtpk(r8[4], r8[5]);
    o.w = cvtpk(r8[6], r8[7]);
    *(uint4*)(X + ((size_t)b * 9 + i) * 512 + lane * 8) = o;
  }
}

// ================= FALLBACK PATH (previous session's verified kernels) =================
__global__ __launch_bounds__(256) void gemm1_bt_bias(
    const void* __restrict__ A, const void* __restrict__ Bw,
    const void* __restrict__ bias, void* out, void* ws,
    const void* __restrict__ curv, int M, int N, int K)
{
  __shared__ __align__(16) u16 As[128 * 32];
  __shared__ __align__(16) u16 Bs[128 * 32];

  const bool f32 = sniff_f32(curv);
  u16* C = f32 ? (u16*)ws : (u16*)out;

  const int t = threadIdx.x;
  const int lane = t & 63;
  const int w = t >> 6;
  const int waveM = w >> 1, waveN = w & 1;
  const int m0 = blockIdx.y * 128;
  const int n0 = blockIdx.x * 128;

  floatx4 acc[4][4];
#pragma unroll
  for (int i = 0; i < 4; i++)
#pragma unroll
    for (int j = 0; j < 4; j++) {
      acc[i][j][0] = 0.f; acc[i][j][1] = 0.f;
      acc[i][j][2] = 0.f; acc[i][j][3] = 0.f;
    }

  const int r0 = t >> 2;
  const int c0 = (t & 3) * 8;
  const size_t oa0 = (size_t)(m0 + r0) * K + c0;
  const size_t oa1 = (size_t)(m0 + 64 + r0) * K + c0;
  const size_t ob0 = (size_t)(n0 + r0) * K + c0;
  const size_t ob1 = (size_t)(n0 + 64 + r0) * K + c0;

  for (int k0 = 0; k0 < K; k0 += 32) {
    uint4 a0 = load8bf(A, oa0 + k0, f32);
    uint4 a1 = load8bf(A, oa1 + k0, f32);
    uint4 b0 = load8bf(Bw, ob0 + k0, f32);
    uint4 b1 = load8bf(Bw, ob1 + k0, f32);
    __syncthreads();
    *(uint4*)(As + t * 8) = a0;
    *(uint4*)(As + 2048 + t * 8) = a1;
    *(uint4*)(Bs + t * 8) = b0;
    *(uint4*)(Bs + 2048 + t * 8) = b1;
    __syncthreads();

    bf16x8 af[4], bfr[4];
    const int am = waveM * 64 + (lane & 15);
    const int bn = waveN * 64 + (lane & 15);
    const int kq = (lane >> 4) * 8;
#pragma unroll
    for (int mt = 0; mt < 4; mt++)
      af[mt] = *(const bf16x8*)(As + (am + mt * 16) * 32 + kq);
#pragma unroll
    for (int nt = 0; nt < 4; nt++)
      bfr[nt] = *(const bf16x8*)(Bs + (bn + nt * 16) * 32 + kq);
#pragma unroll
    for (int mt = 0; mt < 4; mt++)
#pragma unroll
      for (int nt = 0; nt < 4; nt++)
        acc[mt][nt] = __builtin_amdgcn_mfma_f32_16x16x32_bf16(af[mt], bfr[nt], acc[mt][nt], 0, 0, 0);
  }

  const int quad = lane >> 4;
  const int cl = lane & 15;
#pragma unroll
  for (int mt = 0; mt < 4; mt++)
#pragma unroll
    for (int nt = 0; nt < 4; nt++) {
      const int col = n0 + waveN * 64 + nt * 16 + cl;
      const float bs = f32 ? ((const float*)bias)[col] : bf2f(((const u16*)bias)[col]);
#pragma unroll
      for (int r = 0; r < 4; r++) {
        const int row = m0 + waveM * 64 + mt * 16 + quad * 4 + r;
        C[(size_t)row * N + col] = f2bf(acc[mt][nt][r] + bs);
      }
    }
}

__global__ __launch_bounds__(256) void gemm2_fullN(
    const void* __restrict__ Bw, const void* __restrict__ bias,
    void* out, void* ws, const void* __restrict__ curv,
    int M, int N, int K)
{
  __shared__ __align__(16) u16 As[32 * 32];
  __shared__ __align__(16) u16 Bs[512 * 32];

  const bool f32 = sniff_f32(curv);
  const u16* A = f32 ? (const u16*)ws : (const u16*)out;

  const int t = threadIdx.x;
  const int lane = t & 63;
  const int w = t >> 6;
  const int m0 = blockIdx.x * 32;

  floatx4 acc[2][8];
#pragma unroll
  for (int i = 0; i < 2; i++)
#pragma unroll
    for (int j = 0; j < 8; j++) {
      acc[i][j][0] = 0.f; acc[i][j][1] = 0.f;
      acc[i][j][2] = 0.f; acc[i][j][3] = 0.f;
    }

  const int r0 = t >> 2;
  const int c0 = (t & 3) * 8;

  for (int k0 = 0; k0 < K; k0 += 32) {
    uint4 av = make_uint4(0, 0, 0, 0);
    if (t < 128)
      av = *(const uint4*)(A + (size_t)(m0 + r0) * K + k0 + c0);
    uint4 bv[8];
#pragma unroll
    for (int q = 0; q < 8; q++)
      bv[q] = load8bf(Bw, (size_t)(q * 64 + r0) * K + k0 + c0, f32);
    __syncthreads();
    if (t < 128) *(uint4*)(As + t * 8) = av;
#pragma unroll
    for (int q = 0; q < 8; q++)
      *(uint4*)(Bs + q * 2048 + t * 8) = bv[q];
    __syncthreads();

    bf16x8 af[2], bfr[8];
    const int ml = lane & 15;
    const int kq = (lane >> 4) * 8;
#pragma unroll
    for (int mt = 0; mt < 2; mt++)
      af[mt] = *(const bf16x8*)(As + (mt * 16 + ml) * 32 + kq);
#pragma unroll
    for (int nt = 0; nt < 8; nt++)
      bfr[nt] = *(const bf16x8*)(Bs + (w * 128 + nt * 16 + ml) * 32 + kq);
#pragma unroll
    for (int mt = 0; mt < 2; mt++)
#pragma unroll
      for (int nt = 0; nt < 8; nt++)
        acc[mt][nt] = __builtin_amdgcn_mfma_f32_16x16x32_bf16(af[mt], bfr[nt], acc[mt][nt], 0, 0, 0);
  }

  const int quad = lane >> 4;
  const int cl = lane & 15;
#pragma unroll
  for (int mt = 0; mt < 2; mt++)
#pragma unroll
    for (int nt = 0; nt < 8; nt++) {
      const int col = w * 128 + nt * 16 + cl;
      const float bs = f32 ? ((const float*)bias)[col] : bf2f(((const u16*)bias)[col]);
#pragma unroll
      for (int r = 0; r < 4; r++) {
        const int row = m0 + mt * 16 + quad * 4 + r;
        const float v = acc[mt][nt][r] + bs;
        if (f32) ((float*)out)[(size_t)row * N + col] = v;
        else     ((u16*)out)[(size_t)row * N + col] = f2bf(v);
      }
    }
}

// ======================= launch =======================
extern "C" void kernel_launch(void* const* d_in, const int* in_sizes, int n_in,
                              void* d_out, int out_size, void* d_ws, size_t ws_size,
                              hipStream_t stream) {
  const void* nf = d_in[0];
  const void* curv = d_in[1];
  const void* to_w = d_in[2];
  const void* to_b = d_in[3];
  const void* fr_w = d_in[4];
  const void* fr_b = d_in[5];
  const void* mw = d_in[6];

  const int M = 8192 * 9, N = 512, K = 512;
  const size_t XB = (size_t)M * N * 2;       // 75,497,472 B  bf16 intermediate
  const size_t WWB = (size_t)512 * 512 * 2;  // one 512x512 bf16 weight matrix

  // dtype is host-invisible (in_sizes are element counts) -> dtype decisions
  // are device-side sniffs on curvature. Host only picks the scratch LAYOUT.
  // A-conversion is fused into gemm1, so scratch needs only xb + 2 weights.
  // fw_bf must live in ws (gemm2 reads it while writing d_out); tw_bf may
  // spill to d_out (dead before gemm2; never written in bf16 mode).
  u16 *xb = nullptr, *tw_bf = nullptr, *fw_bf = nullptr;
  bool fast = false;
  if (ws_size >= XB + 2 * WWB) {              // everything in ws (R2-verified branch)
    xb    = (u16*)d_ws;
    tw_bf = (u16*)((char*)d_ws + XB);
    fw_bf = (u16*)((char*)d_ws + XB + WWB);
    fast = true;
  } else if (ws_size >= XB + WWB) {           // fw in ws, tw in d_out
    xb    = (u16*)d_ws;
    fw_bf = (u16*)((char*)d_ws + XB);
    tw_bf = (u16*)((char*)d_out + XB);        // f32 out is 2*XB; only written in f32 mode
    fast = true;
  }

  mwnorm<<<81, 64, 0, stream>>>(mw, curv);

  if (fast) {
    cvt_w<<<256, 256, 0, stream>>>((const float*)to_w, (const float*)fr_w,
                                   tw_bf, fw_bf, curv);
    gemm_fast<0, 1><<<dim3(N / 128, M / 128), 256, 0, stream>>>(
        nf, (const u16*)nf, to_w, tw_bf, to_b, xb, curv, M, N, K);
    mobius4<<<8192, 256, 0, stream>>>(xb, xb, mw, curv);
    gemm_fast<1, 0><<<dim3(N / 128, M / 128), 256, 0, stream>>>(
        xb, xb, fr_w, fw_bf, fr_b, d_out, curv, M, N, K);
  } else {
    // fallback: previous session's verified path
    gemm1_bt_bias<<<dim3(N / 128, M / 128), 256, 0, stream>>>(nf, to_w, to_b, d_out, d_ws, curv, M, N, K);
    mobius4<<<8192, 256, 0, stream>>>((u16*)d_ws, (u16*)d_out, mw, curv);
    gemm2_fullN<<<M / 32, 256, 0, stream>>>(fr_w, fr_b, d_out, d_ws, curv, M, N, K);
  }
}